// Round 2
// baseline (542.793 us; speedup 1.0000x reference)
//
#include <hip/hip_runtime.h>
#include <hip/hip_fp16.h>

#define NN 50000
#define EE 800000

typedef float f32x4 __attribute__((ext_vector_type(4)));
typedef _Float16 f16x8 __attribute__((ext_vector_type(8)));
typedef _Float16 f16x4 __attribute__((ext_vector_type(4)));
typedef _Float16 f16x2 __attribute__((ext_vector_type(2)));

// ---------------------------------------------------------------------------
// CSR build
// ---------------------------------------------------------------------------
__global__ void hist_kernel(const int* __restrict__ dst, int* __restrict__ counts, int E) {
    int idx = blockIdx.x * blockDim.x + threadIdx.x;
    int stride = gridDim.x * blockDim.x;
    for (int e = idx; e < E; e += stride)
        atomicAdd(&counts[dst[e]], 1);
}

__global__ void scan_phaseA(const int* __restrict__ counts, int* __restrict__ bsum, int n) {
    __shared__ int buf[256];
    int b = blockIdx.x, t = threadIdx.x;
    int i = b * 256 + t;
    buf[t] = (i < n) ? counts[i] : 0;
    __syncthreads();
#pragma unroll
    for (int off = 128; off; off >>= 1) {
        if (t < off) buf[t] += buf[t + off];
        __syncthreads();
    }
    if (t == 0) bsum[b] = buf[0];
}

__global__ void scan_phaseB(int* __restrict__ bsum, int* __restrict__ row_off_n, int nb) {
    __shared__ int buf[256];
    int t = threadIdx.x;
    int v = (t < nb) ? bsum[t] : 0;
    buf[t] = v;
    __syncthreads();
#pragma unroll
    for (int off = 1; off < 256; off <<= 1) {
        int x = (t >= off) ? buf[t - off] : 0;
        __syncthreads();
        buf[t] += x;
        __syncthreads();
    }
    if (t < nb) bsum[t] = buf[t] - v;       // exclusive block offset
    if (t == 255) *row_off_n = buf[255];    // total -> row_off[N]
}

__global__ void scan_phaseC(const int* __restrict__ counts, const int* __restrict__ bsum,
                            int* __restrict__ row_off, int n) {
    __shared__ int buf[256];
    int b = blockIdx.x, t = threadIdx.x;
    int i = b * 256 + t;
    int v = (i < n) ? counts[i] : 0;
    buf[t] = v;
    __syncthreads();
#pragma unroll
    for (int off = 1; off < 256; off <<= 1) {
        int x = (t >= off) ? buf[t - off] : 0;
        __syncthreads();
        buf[t] += x;
        __syncthreads();
    }
    if (i < n) row_off[i] = bsum[b] + buf[t] - v;
}

__global__ void scatter_kernel(const int* __restrict__ src, const int* __restrict__ dst,
                               const int* __restrict__ row_off, int* __restrict__ cursor,
                               int* __restrict__ esrc, int E) {
    int idx = blockIdx.x * blockDim.x + threadIdx.x;
    int stride = gridDim.x * blockDim.x;
    for (int e = idx; e < E; e += stride) {
        int d = dst[e];
        int pos = row_off[d] + atomicAdd(&cursor[d], 1);
        esrc[pos] = src[e];
    }
}

// ---------------------------------------------------------------------------
// Fused prep: weights -> FRAGMENT-READY fp16 layout, x -> fp16.
// ---------------------------------------------------------------------------
__device__ __forceinline__ void wfrag_store(__half* o, int K, int col, int k, float v) {
    int KS = K >> 5;
    int cgni = col >> 4, l15 = col & 15;
    int ks = k >> 5, qq = (k >> 3) & 3, ee = k & 7;
    size_t flat = ((size_t)(cgni * KS + ks) * 64 + qq * 16 + l15) * 8 + ee;
    o[flat] = __float2half_rn(v);
}

__global__ void prep_all(const float* __restrict__ Wl1, const float* __restrict__ Wr1,
                         const float* __restrict__ Wl2, const float* __restrict__ Wr2,
                         const float* __restrict__ Wl3, const float* __restrict__ Wr3,
                         const float* __restrict__ Wlin,
                         __half* __restrict__ w1, __half* __restrict__ w2,
                         __half* __restrict__ w3, __half* __restrict__ w4,
                         const float* __restrict__ x, __half* __restrict__ xf, int n4x) {
    int idx = blockIdx.x * blockDim.x + threadIdx.x;
    if (idx < 233472) {
        const float* W; __half* o; int K, Nc, roff, li;
        if (idx < 65536) {
            K = 128; Nc = 256; o = w1;
            if (idx < 32768) { W = Wl1; li = idx; roff = 0; }
            else             { W = Wr1; li = idx - 32768; roff = 256; }
        } else if (idx < 196608) {
            K = 256; Nc = 256; o = w2;
            if (idx < 131072) { W = Wl2; li = idx - 65536; roff = 0; }
            else              { W = Wr2; li = idx - 131072; roff = 256; }
        } else if (idx < 229376) {
            K = 256; Nc = 64; o = w3;
            if (idx < 212992) { W = Wl3; li = idx - 196608; roff = 0; }
            else              { W = Wr3; li = idx - 212992; roff = 64; }
        } else {
            K = 64; Nc = 64; o = w4; W = Wlin; li = idx - 229376; roff = 0;
        }
        int k = li / Nc, n = li - k * Nc;
        wfrag_store(o, K, roff + n, k, W[li]);
    } else {
        int xi = idx - 233472;
        if (xi < n4x) {
            float4 v = *(const float4*)(x + (size_t)xi * 4);
            f16x4 h = {(_Float16)v.x, (_Float16)v.y, (_Float16)v.z, (_Float16)v.w};
            *(f16x4*)((_Float16*)xf + (size_t)xi * 4) = h;
        }
    }
}

// ---------------------------------------------------------------------------
// Weight-stationary tall-skinny GEMM (unchanged).
// ---------------------------------------------------------------------------
template <int KS, int COLG>
__global__ __launch_bounds__(COLG * 256) void gemm_ws(
        const __half* __restrict__ A, const __half* __restrict__ Bt,
        int M, int nTiles, int Nc, int splitCol,
        __half* __restrict__ outL, __half* __restrict__ outR,
        float* __restrict__ outF, const float* __restrict__ bias) {
    constexpr int K = KS * 32;
    int tid = threadIdx.x;
    int lane = tid & 63;
    int w = tid >> 6;
    int rs = w & 3;
    int cg = w >> 2;
    int l15 = lane & 15, q = lane >> 4;
    int colbase = blockIdx.y * (COLG * 64) + cg * 64;

    const _Float16* Ap = (const _Float16*)A;
    const f16x8* Bf = (const f16x8*)Bt;
    int cgni0 = (blockIdx.y * COLG + cg) * 4;

    f16x8 bfrag[KS][4];
#pragma unroll
    for (int ks = 0; ks < KS; ++ks)
#pragma unroll
        for (int ni = 0; ni < 4; ++ni)
            bfrag[ks][ni] = Bf[((size_t)(cgni0 + ni) * KS + ks) * 64 + lane];

    int tile = blockIdx.x;
    if (tile >= nTiles) return;

    f16x8 afrag[KS];
    {
        int row = tile * 64 + rs * 16 + l15;
        if (row >= M) row = M - 1;
        const _Float16* ap = Ap + (size_t)row * K + q * 8;
#pragma unroll
        for (int ks = 0; ks < KS; ++ks) afrag[ks] = *(const f16x8*)(ap + ks * 32);
    }

    while (true) {
        int next = tile + gridDim.x;
        bool has = (next < nTiles);
        f16x8 anext[KS];
        if (has) {
            int row = next * 64 + rs * 16 + l15;
            if (row >= M) row = M - 1;
            const _Float16* ap = Ap + (size_t)row * K + q * 8;
#pragma unroll
            for (int ks = 0; ks < KS; ++ks) anext[ks] = *(const f16x8*)(ap + ks * 32);
        }

        f32x4 acc[4] = {};
#pragma unroll
        for (int ks = 0; ks < KS; ++ks)
#pragma unroll
            for (int ni = 0; ni < 4; ++ni)
                acc[ni] = __builtin_amdgcn_mfma_f32_16x16x32_f16(afrag[ks], bfrag[ks][ni], acc[ni], 0, 0, 0);

#pragma unroll
        for (int ni = 0; ni < 4; ++ni) {
            int gc = colbase + ni * 16 + l15;
            if (outF) {
                float bv = bias ? bias[gc] : 0.f;
#pragma unroll
                for (int r = 0; r < 4; ++r) {
                    int gr = tile * 64 + rs * 16 + q * 4 + r;
                    if (gr < M) outF[(size_t)gr * Nc + gc] = acc[ni][r] + bv;
                }
            } else {
                __half* dp = outL; int cc = gc;
                if (gc >= splitCol) { dp = outR; cc = gc - splitCol; }
#pragma unroll
                for (int r = 0; r < 4; ++r) {
                    int gr = tile * 64 + rs * 16 + q * 4 + r;
                    if (gr < M) dp[(size_t)gr * splitCol + cc] = __float2half_rn(acc[ni][r]);
                }
            }
        }
        if (!has) break;
#pragma unroll
        for (int ks = 0; ks < KS; ++ks) afrag[ks] = anext[ks];
        tile = next;
    }
}

// ---------------------------------------------------------------------------
// DPP helpers: butterfly adds on the VALU pipe.
//   0xB1 = quad_perm [1,0,3,2]  (xor 1)
//   0x4E = quad_perm [2,3,0,1]  (xor 2)
//   0x141 = row_half_mirror     (combines the two quads of an 8-lane group
//           once lanes within each quad are uniform)
// ---------------------------------------------------------------------------
template <int CTRL>
__device__ __forceinline__ float dpp_add_f32(float x) {
    int y = __builtin_amdgcn_mov_dpp(__float_as_int(x), CTRL, 0xF, 0xF, true);
    return x + __int_as_float(y);
}

// ---------------------------------------------------------------------------
// GATv2 gather, H=4 x C=64. One wave per dst node, 16 lanes/edge x 4 slots.
// R13: copy-free 4-buffer modulo pipeline.
//   - prologue issues 8 gathers back-to-back (16 edges = avg degree, MLP 8)
//   - each phase consumes buffer k and refills it IN PLACE for e+16
//     (consumption distance = 3 phases, no register copies -> no forced
//     early vmcnt wait; R12's g0=h0 rotation movs collapsed the pipeline,
//     visible as VGPR_Count=36)
//   - refills gated by wave-uniform branch (skipped for deg<=16 nodes)
// ---------------------------------------------------------------------------
__global__ __launch_bounds__(256, 4) void gat_gather_h4(
        const __half* __restrict__ xl, const __half* __restrict__ xr,
        const float* __restrict__ att, const float* __restrict__ bias,
        const int* __restrict__ row_off, const int* __restrict__ esrc,
        __half* __restrict__ out, int n) {
    const float LOG2E = 1.44269504f;
    int wave = threadIdx.x >> 6;
    int lane = threadIdx.x & 63;
    int node = blockIdx.x * 4 + wave;
    if (node >= n) return;
    int eslot = lane >> 4;        // 0..3 : which edge of the phase
    unsigned j = lane & 15;       // channels 16j .. 16j+15

    const uint4* xl16 = (const uint4*)xl;   // 32 uint4 per row
    unsigned jo = 2u * j;

    f16x2 xrv[8];
    *(uint4*)(&xrv[0]) = ((const uint4*)xr)[((unsigned)node << 5) + jo];
    *(uint4*)(&xrv[4]) = ((const uint4*)xr)[((unsigned)node << 5) + jo + 1];

    float4 a0 = *(const float4*)(att + j * 16);
    float4 a1 = *(const float4*)(att + j * 16 + 4);
    float4 a2 = *(const float4*)(att + j * 16 + 8);
    float4 a3 = *(const float4*)(att + j * 16 + 12);
    f16x2 atv[8] = {
        {(_Float16)(a0.x * LOG2E), (_Float16)(a0.y * LOG2E)},
        {(_Float16)(a0.z * LOG2E), (_Float16)(a0.w * LOG2E)},
        {(_Float16)(a1.x * LOG2E), (_Float16)(a1.y * LOG2E)},
        {(_Float16)(a1.z * LOG2E), (_Float16)(a1.w * LOG2E)},
        {(_Float16)(a2.x * LOG2E), (_Float16)(a2.y * LOG2E)},
        {(_Float16)(a2.z * LOG2E), (_Float16)(a2.w * LOG2E)},
        {(_Float16)(a3.x * LOG2E), (_Float16)(a3.y * LOG2E)},
        {(_Float16)(a3.z * LOG2E), (_Float16)(a3.w * LOG2E)}};
    const f16x2 k02 = {(_Float16)0.2f, (_Float16)0.2f};

    float acc[16] = {};
    float L = 0.f;

    int e0 = row_off[node], e1 = row_off[node + 1];
    int elast = (e1 > e0) ? e1 - 1 : e0;

    // prologue: srcs + 8 gathers for edges e0 .. e0+15
    int sA = esrc[min(e0 +  0 + eslot, elast)];
    int sB = esrc[min(e0 +  4 + eslot, elast)];
    int sC = esrc[min(e0 +  8 + eslot, elast)];
    int sD = esrc[min(e0 + 12 + eslot, elast)];
    uint4 A0 = xl16[((unsigned)sA << 5) + jo], A1 = xl16[((unsigned)sA << 5) + jo + 1];
    uint4 B0 = xl16[((unsigned)sB << 5) + jo], B1 = xl16[((unsigned)sB << 5) + jo + 1];
    uint4 C0 = xl16[((unsigned)sC << 5) + jo], C1 = xl16[((unsigned)sC << 5) + jo + 1];
    uint4 D0 = xl16[((unsigned)sD << 5) + jo], D1 = xl16[((unsigned)sD << 5) + jo + 1];

#define H4_PHASE(R0, R1, EB)                                                  \
    {                                                                         \
        f16x2 v[8];                                                           \
        *(uint4*)(&v[0]) = R0;                                                \
        *(uint4*)(&v[4]) = R1;                                                \
        float t0 = 0.f, t1 = 0.f;                                             \
        _Pragma("unroll")                                                     \
        for (int k = 0; k < 4; ++k) {                                         \
            f16x2 sa = v[k] + xrv[k];                                         \
            f16x2 ra = __builtin_elementwise_max(sa, sa * k02);               \
            t0 = __builtin_amdgcn_fdot2(ra, atv[k], t0, false);               \
            f16x2 sb = v[k + 4] + xrv[k + 4];                                 \
            f16x2 rb = __builtin_elementwise_max(sb, sb * k02);               \
            t1 = __builtin_amdgcn_fdot2(rb, atv[k + 4], t1, false);           \
        }                                                                     \
        float t = t0 + t1;                                                    \
        t = dpp_add_f32<0xB1>(t);                                             \
        t = dpp_add_f32<0x4E>(t);                                             \
        float p = exp2f(t);                                                   \
        p = ((EB) + eslot < e1) ? p : 0.f;                                    \
        L += p;                                                               \
        _Pragma("unroll")                                                     \
        for (int k = 0; k < 8; ++k) {                                         \
            acc[2 * k]     = fmaf((float)v[k].x, p, acc[2 * k]);              \
            acc[2 * k + 1] = fmaf((float)v[k].y, p, acc[2 * k + 1]);          \
        }                                                                     \
    }

    for (int e = e0; e < e1; e += 16) {
        bool more = (e + 16 < e1);
        int nsA = e0, nsB = e0, nsC = e0, nsD = e0;
        if (more) {
            nsA = esrc[min(e + 16 + eslot, elast)];
            nsB = esrc[min(e + 20 + eslot, elast)];
            nsC = esrc[min(e + 24 + eslot, elast)];
            nsD = esrc[min(e + 28 + eslot, elast)];
        }
        H4_PHASE(A0, A1, e)
        if (more) {
            A0 = xl16[((unsigned)nsA << 5) + jo];
            A1 = xl16[((unsigned)nsA << 5) + jo + 1];
        }
        H4_PHASE(B0, B1, e + 4)
        if (more) {
            B0 = xl16[((unsigned)nsB << 5) + jo];
            B1 = xl16[((unsigned)nsB << 5) + jo + 1];
        }
        H4_PHASE(C0, C1, e + 8)
        if (more) {
            C0 = xl16[((unsigned)nsC << 5) + jo];
            C1 = xl16[((unsigned)nsC << 5) + jo + 1];
        }
        H4_PHASE(D0, D1, e + 12)
        if (more) {
            D0 = xl16[((unsigned)nsD << 5) + jo];
            D1 = xl16[((unsigned)nsD << 5) + jo + 1];
        }
    }
#undef H4_PHASE

    // reduce partial sums across the 4 edge-slots (once per node)
#pragma unroll
    for (int k = 0; k < 16; ++k) {
        acc[k] += __shfl_xor(acc[k], 16);
        acc[k] += __shfl_xor(acc[k], 32);
    }
    L += __shfl_xor(L, 16);
    L += __shfl_xor(L, 32);

    if (eslot == 0) {
        float inv = 1.f / (L + 1e-16f);
        float4 b0 = *(const float4*)(bias + j * 16);
        float4 b1v = *(const float4*)(bias + j * 16 + 4);
        float4 b2v = *(const float4*)(bias + j * 16 + 8);
        float4 b3v = *(const float4*)(bias + j * 16 + 12);
        float bb[16] = {b0.x,  b0.y,  b0.z,  b0.w,  b1v.x, b1v.y, b1v.z, b1v.w,
                        b2v.x, b2v.y, b2v.z, b2v.w, b3v.x, b3v.y, b3v.z, b3v.w};
        f16x8 o0, o1;
#pragma unroll
        for (int k = 0; k < 8; ++k) {
            float vA = acc[k] * inv + bb[k];
            vA = vA > 0.f ? vA : __expf(vA) - 1.f;   // ELU
            o0[k] = (_Float16)vA;
            float vB = acc[k + 8] * inv + bb[k + 8];
            vB = vB > 0.f ? vB : __expf(vB) - 1.f;
            o1[k] = (_Float16)vB;
        }
        _Float16* op = (_Float16*)out + ((size_t)node << 8) + j * 16;
        *(f16x8*)op = o0;
        *(f16x8*)(op + 8) = o1;
    }
}

// ---------------------------------------------------------------------------
// GATv2 gather, H=1 x C=64 (no ELU). 8 lanes/edge x 8 slots, same copy-free
// 4-buffer pipeline (32 edges per loop iteration; prologue covers 2x avg deg).
// ---------------------------------------------------------------------------
__global__ __launch_bounds__(256, 4) void gat_gather_h1(
        const __half* __restrict__ xl, const __half* __restrict__ xr,
        const float* __restrict__ att, const float* __restrict__ bias,
        const int* __restrict__ row_off, const int* __restrict__ esrc,
        __half* __restrict__ out, int n) {
    const float LOG2E = 1.44269504f;
    int wave = threadIdx.x >> 6;
    int lane = threadIdx.x & 63;
    int node = blockIdx.x * 4 + wave;
    if (node >= n) return;
    int eslot = lane >> 3;        // 0..7
    unsigned j = lane & 7;        // channels 8j .. 8j+7

    const uint4* xl16 = (const uint4*)xl;   // 8 uint4 per row

    f16x2 xrv[4];
    *(uint4*)(&xrv[0]) = ((const uint4*)xr)[((unsigned)node << 3) + j];

    float4 a0 = *(const float4*)(att + j * 8);
    float4 a1 = *(const float4*)(att + j * 8 + 4);
    f16x2 atv[4] = {
        {(_Float16)(a0.x * LOG2E), (_Float16)(a0.y * LOG2E)},
        {(_Float16)(a0.z * LOG2E), (_Float16)(a0.w * LOG2E)},
        {(_Float16)(a1.x * LOG2E), (_Float16)(a1.y * LOG2E)},
        {(_Float16)(a1.z * LOG2E), (_Float16)(a1.w * LOG2E)}};
    const f16x2 k02 = {(_Float16)0.2f, (_Float16)0.2f};

    float acc[8] = {};
    float L = 0.f;

    int e0 = row_off[node], e1 = row_off[node + 1];
    int elast = (e1 > e0) ? e1 - 1 : e0;

    // prologue: srcs + 4 gathers for edges e0 .. e0+31
    int sA = esrc[min(e0 +  0 + eslot, elast)];
    int sB = esrc[min(e0 +  8 + eslot, elast)];
    int sC = esrc[min(e0 + 16 + eslot, elast)];
    int sD = esrc[min(e0 + 24 + eslot, elast)];
    uint4 A = xl16[((unsigned)sA << 3) + j];
    uint4 B = xl16[((unsigned)sB << 3) + j];
    uint4 C = xl16[((unsigned)sC << 3) + j];
    uint4 D = xl16[((unsigned)sD << 3) + j];

#define H1_PHASE(R, EB)                                                       \
    {                                                                         \
        f16x2 v[4];                                                           \
        *(uint4*)(&v[0]) = R;                                                 \
        float t0 = 0.f, t1 = 0.f;                                             \
        {                                                                     \
            f16x2 s0 = v[0] + xrv[0];                                         \
            f16x2 r0 = __builtin_elementwise_max(s0, s0 * k02);               \
            t0 = __builtin_amdgcn_fdot2(r0, atv[0], t0, false);               \
            f16x2 s1 = v[1] + xrv[1];                                         \
            f16x2 r1 = __builtin_elementwise_max(s1, s1 * k02);               \
            t0 = __builtin_amdgcn_fdot2(r1, atv[1], t0, false);               \
            f16x2 s2 = v[2] + xrv[2];                                         \
            f16x2 r2 = __builtin_elementwise_max(s2, s2 * k02);               \
            t1 = __builtin_amdgcn_fdot2(r2, atv[2], t1, false);               \
            f16x2 s3 = v[3] + xrv[3];                                         \
            f16x2 r3 = __builtin_elementwise_max(s3, s3 * k02);               \
            t1 = __builtin_amdgcn_fdot2(r3, atv[3], t1, false);               \
        }                                                                     \
        float t = t0 + t1;                                                    \
        t = dpp_add_f32<0xB1>(t);                                             \
        t = dpp_add_f32<0x4E>(t);                                             \
        t = dpp_add_f32<0x141>(t);                                            \
        float p = exp2f(t);                                                   \
        p = ((EB) + eslot < e1) ? p : 0.f;                                    \
        L += p;                                                               \
        _Pragma("unroll")                                                     \
        for (int k = 0; k < 4; ++k) {                                         \
            acc[2 * k]     = fmaf((float)v[k].x, p, acc[2 * k]);              \
            acc[2 * k + 1] = fmaf((float)v[k].y, p, acc[2 * k + 1]);          \
        }                                                                     \
    }

    for (int e = e0; e < e1; e += 32) {
        bool more = (e + 32 < e1);
        int nsA = e0, nsB = e0, nsC = e0, nsD = e0;
        if (more) {
            nsA = esrc[min(e + 32 + eslot, elast)];
            nsB = esrc[min(e + 40 + eslot, elast)];
            nsC = esrc[min(e + 48 + eslot, elast)];
            nsD = esrc[min(e + 56 + eslot, elast)];
        }
        H1_PHASE(A, e)
        if (more) A = xl16[((unsigned)nsA << 3) + j];
        H1_PHASE(B, e + 8)
        if (more) B = xl16[((unsigned)nsB << 3) + j];
        H1_PHASE(C, e + 16)
        if (more) C = xl16[((unsigned)nsC << 3) + j];
        H1_PHASE(D, e + 24)
        if (more) D = xl16[((unsigned)nsD << 3) + j];
    }
#undef H1_PHASE

    // reduce partial sums across the 8 edge-slots
#pragma unroll
    for (int k = 0; k < 8; ++k) {
        acc[k] += __shfl_xor(acc[k], 8);
        acc[k] += __shfl_xor(acc[k], 16);
        acc[k] += __shfl_xor(acc[k], 32);
    }
    L += __shfl_xor(L, 8);
    L += __shfl_xor(L, 16);
    L += __shfl_xor(L, 32);

    if (eslot == 0) {
        float inv = 1.f / (L + 1e-16f);
        float4 b0 = *(const float4*)(bias + j * 8);
        float4 b1v = *(const float4*)(bias + j * 8 + 4);
        float bb[8] = {b0.x, b0.y, b0.z, b0.w, b1v.x, b1v.y, b1v.z, b1v.w};
        f16x8 ov;
#pragma unroll
        for (int k = 0; k < 8; ++k)
            ov[k] = (_Float16)(acc[k] * inv + bb[k]);
        *(f16x8*)((_Float16*)out + ((size_t)node << 6) + j * 8) = ov;
    }
}

// ---------------------------------------------------------------------------
extern "C" void kernel_launch(void* const* d_in, const int* in_sizes, int n_in,
                              void* d_out, int out_size, void* d_ws, size_t ws_size,
                              hipStream_t stream) {
    const float* x    = (const float*)d_in[0];
    const float* Wl1  = (const float*)d_in[1];
    const float* Wr1  = (const float*)d_in[2];
    const float* att1 = (const float*)d_in[3];
    const float* b1   = (const float*)d_in[4];
    const float* Wl2  = (const float*)d_in[5];
    const float* Wr2  = (const float*)d_in[6];
    const float* att2 = (const float*)d_in[7];
    const float* b2   = (const float*)d_in[8];
    const float* Wl3  = (const float*)d_in[9];
    const float* Wr3  = (const float*)d_in[10];
    const float* att3 = (const float*)d_in[11];
    const float* b3   = (const float*)d_in[12];
    const float* Wlin = (const float*)d_in[13];
    const float* blin = (const float*)d_in[14];
    const int*   ei   = (const int*)d_in[15];
    const int* src = ei;
    const int* dst = ei + EE;

    const int N = NN, E = EE;
    const int NB = (N + 255) / 256;             // 196 scan blocks

    __half* xf = (__half*)d_ws;                 // N*128
    __half* xl = xf + (size_t)N * 128;          // N*256
    __half* xr = xl + (size_t)N * 256;          // N*256
    __half* H  = xr + (size_t)N * 256;          // N*256
    __half* G  = H + (size_t)N * 256;           // N*64
    __half* w1 = G + (size_t)N * 64;            // 65536  frag-layout
    __half* w2 = w1 + 65536;                    // 131072
    __half* w3 = w2 + 131072;                   // 32768
    __half* w4 = w3 + 32768;                    // 4096
    int* row_off = (int*)(w4 + 4096);           // N+1
    int* tmp     = row_off + (N + 1);           // 2N (counts | cursor)
    int* esrc    = tmp + 2 * N;                 // E
    int* bsum    = esrc + E;                    // 256

    // --- build CSR by dst ---
    hipMemsetAsync(tmp, 0, (size_t)2 * N * sizeof(int), stream);
    hist_kernel<<<1024, 256, 0, stream>>>(dst, tmp, E);
    scan_phaseA<<<NB, 256, 0, stream>>>(tmp, bsum, N);
    scan_phaseB<<<1, 256, 0, stream>>>(bsum, row_off + N, NB);
    scan_phaseC<<<NB, 256, 0, stream>>>(tmp, bsum, row_off, N);
    scatter_kernel<<<1024, 256, 0, stream>>>(src, dst, row_off, tmp + N, esrc, E);

    // --- weights (fragment layout) + x -> fp16 ---
    int n4x = N * 128 / 4;
    prep_all<<<(233472 + n4x + 255) / 256, 256, 0, stream>>>(
        Wl1, Wr1, Wl2, Wr2, Wl3, Wr3, Wlin, w1, w2, w3, w4, x, xf, n4x);

    int nTiles = (N + 63) / 64;                 // 782
    int gatherBlocks = (N + 3) / 4;

    // --- layer 1: xf[128] @ w1 -> xl,xr fp16 ---
    gemm_ws<4, 2><<<dim3(128, 4), 512, 0, stream>>>(
        xf, w1, N, nTiles, 512, 256, xl, xr, nullptr, nullptr);
    gat_gather_h4<<<gatherBlocks, 256, 0, stream>>>(xl, xr, att1, b1, row_off, esrc, H, N);

    // --- layer 2: H[256] @ w2 -> xl,xr ---
    gemm_ws<8, 2><<<dim3(128, 4), 512, 0, stream>>>(
        H, w2, N, nTiles, 512, 256, xl, xr, nullptr, nullptr);
    gat_gather_h4<<<gatherBlocks, 256, 0, stream>>>(xl, xr, att2, b2, row_off, esrc, H, N);

    // --- layer 3: H[256] @ w3 -> xl,xr ([N][64] each) ---
    gemm_ws<8, 2><<<dim3(256, 1), 512, 0, stream>>>(
        H, w3, N, nTiles, 128, 64, xl, xr, nullptr, nullptr);
    gat_gather_h1<<<gatherBlocks, 256, 0, stream>>>(xl, xr, att3, b3, row_off, esrc, G, N);

    // --- final: G[64] @ w4 + blin -> d_out fp32 ---
    gemm_ws<2, 1><<<dim3(512, 1), 256, 0, stream>>>(
        G, w4, N, nTiles, 64, 64, nullptr, nullptr, (float*)d_out, blin);
}

// Round 3
// 477.546 us; speedup vs baseline: 1.1366x; 1.1366x over previous
//
#include <hip/hip_runtime.h>
#include <hip/hip_fp16.h>

#define NN 50000
#define EE 800000

typedef float f32x4 __attribute__((ext_vector_type(4)));
typedef _Float16 f16x8 __attribute__((ext_vector_type(8)));
typedef _Float16 f16x4 __attribute__((ext_vector_type(4)));
typedef _Float16 f16x2 __attribute__((ext_vector_type(2)));

// ---------------------------------------------------------------------------
// CSR build
// ---------------------------------------------------------------------------
__global__ void hist_kernel(const int* __restrict__ dst, int* __restrict__ counts, int E) {
    int idx = blockIdx.x * blockDim.x + threadIdx.x;
    int stride = gridDim.x * blockDim.x;
    for (int e = idx; e < E; e += stride)
        atomicAdd(&counts[dst[e]], 1);
}

__global__ void scan_phaseA(const int* __restrict__ counts, int* __restrict__ bsum, int n) {
    __shared__ int buf[256];
    int b = blockIdx.x, t = threadIdx.x;
    int i = b * 256 + t;
    buf[t] = (i < n) ? counts[i] : 0;
    __syncthreads();
#pragma unroll
    for (int off = 128; off; off >>= 1) {
        if (t < off) buf[t] += buf[t + off];
        __syncthreads();
    }
    if (t == 0) bsum[b] = buf[0];
}

__global__ void scan_phaseB(int* __restrict__ bsum, int* __restrict__ row_off_n, int nb) {
    __shared__ int buf[256];
    int t = threadIdx.x;
    int v = (t < nb) ? bsum[t] : 0;
    buf[t] = v;
    __syncthreads();
#pragma unroll
    for (int off = 1; off < 256; off <<= 1) {
        int x = (t >= off) ? buf[t - off] : 0;
        __syncthreads();
        buf[t] += x;
        __syncthreads();
    }
    if (t < nb) bsum[t] = buf[t] - v;       // exclusive block offset
    if (t == 255) *row_off_n = buf[255];    // total -> row_off[N]
}

__global__ void scan_phaseC(const int* __restrict__ counts, const int* __restrict__ bsum,
                            int* __restrict__ row_off, int n) {
    __shared__ int buf[256];
    int b = blockIdx.x, t = threadIdx.x;
    int i = b * 256 + t;
    int v = (i < n) ? counts[i] : 0;
    buf[t] = v;
    __syncthreads();
#pragma unroll
    for (int off = 1; off < 256; off <<= 1) {
        int x = (t >= off) ? buf[t - off] : 0;
        __syncthreads();
        buf[t] += x;
        __syncthreads();
    }
    if (i < n) row_off[i] = bsum[b] + buf[t] - v;
}

__global__ void scatter_kernel(const int* __restrict__ src, const int* __restrict__ dst,
                               const int* __restrict__ row_off, int* __restrict__ cursor,
                               int* __restrict__ esrc, int E) {
    int idx = blockIdx.x * blockDim.x + threadIdx.x;
    int stride = gridDim.x * blockDim.x;
    for (int e = idx; e < E; e += stride) {
        int d = dst[e];
        int pos = row_off[d] + atomicAdd(&cursor[d], 1);
        esrc[pos] = src[e];
    }
}

// ---------------------------------------------------------------------------
// Fused prep: weights -> FRAGMENT-READY fp16 layout, x -> fp16.
// ---------------------------------------------------------------------------
__device__ __forceinline__ void wfrag_store(__half* o, int K, int col, int k, float v) {
    int KS = K >> 5;
    int cgni = col >> 4, l15 = col & 15;
    int ks = k >> 5, qq = (k >> 3) & 3, ee = k & 7;
    size_t flat = ((size_t)(cgni * KS + ks) * 64 + qq * 16 + l15) * 8 + ee;
    o[flat] = __float2half_rn(v);
}

__global__ void prep_all(const float* __restrict__ Wl1, const float* __restrict__ Wr1,
                         const float* __restrict__ Wl2, const float* __restrict__ Wr2,
                         const float* __restrict__ Wl3, const float* __restrict__ Wr3,
                         const float* __restrict__ Wlin,
                         __half* __restrict__ w1, __half* __restrict__ w2,
                         __half* __restrict__ w3, __half* __restrict__ w4,
                         const float* __restrict__ x, __half* __restrict__ xf, int n4x) {
    int idx = blockIdx.x * blockDim.x + threadIdx.x;
    if (idx < 233472) {
        const float* W; __half* o; int K, Nc, roff, li;
        if (idx < 65536) {
            K = 128; Nc = 256; o = w1;
            if (idx < 32768) { W = Wl1; li = idx; roff = 0; }
            else             { W = Wr1; li = idx - 32768; roff = 256; }
        } else if (idx < 196608) {
            K = 256; Nc = 256; o = w2;
            if (idx < 131072) { W = Wl2; li = idx - 65536; roff = 0; }
            else              { W = Wr2; li = idx - 131072; roff = 256; }
        } else if (idx < 229376) {
            K = 256; Nc = 64; o = w3;
            if (idx < 212992) { W = Wl3; li = idx - 196608; roff = 0; }
            else              { W = Wr3; li = idx - 212992; roff = 64; }
        } else {
            K = 64; Nc = 64; o = w4; W = Wlin; li = idx - 229376; roff = 0;
        }
        int k = li / Nc, n = li - k * Nc;
        wfrag_store(o, K, roff + n, k, W[li]);
    } else {
        int xi = idx - 233472;
        if (xi < n4x) {
            float4 v = *(const float4*)(x + (size_t)xi * 4);
            f16x4 h = {(_Float16)v.x, (_Float16)v.y, (_Float16)v.z, (_Float16)v.w};
            *(f16x4*)((_Float16*)xf + (size_t)xi * 4) = h;
        }
    }
}

// ---------------------------------------------------------------------------
// Weight-stationary tall-skinny GEMM (unchanged).
// ---------------------------------------------------------------------------
template <int KS, int COLG>
__global__ __launch_bounds__(COLG * 256) void gemm_ws(
        const __half* __restrict__ A, const __half* __restrict__ Bt,
        int M, int nTiles, int Nc, int splitCol,
        __half* __restrict__ outL, __half* __restrict__ outR,
        float* __restrict__ outF, const float* __restrict__ bias) {
    constexpr int K = KS * 32;
    int tid = threadIdx.x;
    int lane = tid & 63;
    int w = tid >> 6;
    int rs = w & 3;
    int cg = w >> 2;
    int l15 = lane & 15, q = lane >> 4;
    int colbase = blockIdx.y * (COLG * 64) + cg * 64;

    const _Float16* Ap = (const _Float16*)A;
    const f16x8* Bf = (const f16x8*)Bt;
    int cgni0 = (blockIdx.y * COLG + cg) * 4;

    f16x8 bfrag[KS][4];
#pragma unroll
    for (int ks = 0; ks < KS; ++ks)
#pragma unroll
        for (int ni = 0; ni < 4; ++ni)
            bfrag[ks][ni] = Bf[((size_t)(cgni0 + ni) * KS + ks) * 64 + lane];

    int tile = blockIdx.x;
    if (tile >= nTiles) return;

    f16x8 afrag[KS];
    {
        int row = tile * 64 + rs * 16 + l15;
        if (row >= M) row = M - 1;
        const _Float16* ap = Ap + (size_t)row * K + q * 8;
#pragma unroll
        for (int ks = 0; ks < KS; ++ks) afrag[ks] = *(const f16x8*)(ap + ks * 32);
    }

    while (true) {
        int next = tile + gridDim.x;
        bool has = (next < nTiles);
        f16x8 anext[KS];
        if (has) {
            int row = next * 64 + rs * 16 + l15;
            if (row >= M) row = M - 1;
            const _Float16* ap = Ap + (size_t)row * K + q * 8;
#pragma unroll
            for (int ks = 0; ks < KS; ++ks) anext[ks] = *(const f16x8*)(ap + ks * 32);
        }

        f32x4 acc[4] = {};
#pragma unroll
        for (int ks = 0; ks < KS; ++ks)
#pragma unroll
            for (int ni = 0; ni < 4; ++ni)
                acc[ni] = __builtin_amdgcn_mfma_f32_16x16x32_f16(afrag[ks], bfrag[ks][ni], acc[ni], 0, 0, 0);

#pragma unroll
        for (int ni = 0; ni < 4; ++ni) {
            int gc = colbase + ni * 16 + l15;
            if (outF) {
                float bv = bias ? bias[gc] : 0.f;
#pragma unroll
                for (int r = 0; r < 4; ++r) {
                    int gr = tile * 64 + rs * 16 + q * 4 + r;
                    if (gr < M) outF[(size_t)gr * Nc + gc] = acc[ni][r] + bv;
                }
            } else {
                __half* dp = outL; int cc = gc;
                if (gc >= splitCol) { dp = outR; cc = gc - splitCol; }
#pragma unroll
                for (int r = 0; r < 4; ++r) {
                    int gr = tile * 64 + rs * 16 + q * 4 + r;
                    if (gr < M) dp[(size_t)gr * splitCol + cc] = __float2half_rn(acc[ni][r]);
                }
            }
        }
        if (!has) break;
#pragma unroll
        for (int ks = 0; ks < KS; ++ks) afrag[ks] = anext[ks];
        tile = next;
    }
}

// ---------------------------------------------------------------------------
// DPP helpers: butterfly adds on the VALU pipe.
//   0xB1 = quad_perm [1,0,3,2]  (xor 1)
//   0x4E = quad_perm [2,3,0,1]  (xor 2)
//   0x141 = row_half_mirror     (combines the two quads of an 8-lane group)
// ---------------------------------------------------------------------------
template <int CTRL>
__device__ __forceinline__ float dpp_add_f32(float x) {
    int y = __builtin_amdgcn_mov_dpp(__float_as_int(x), CTRL, 0xF, 0xF, true);
    return x + __int_as_float(y);
}

// ---------------------------------------------------------------------------
// GATv2 gather, H=4 x C=64. One wave per dst node, 16 lanes/edge x 4 slots.
// R14: 3-buffer copy-free rotation, UNCONDITIONAL clamp-addressed refills.
//   - R13's 4-buffer + conditional (if(more)) refills made the allocator
//     demote buffers to scratch: WRITE_SIZE 25->176 MB, dur 71->113us.
//   - Here each phase redefines its own buffer via a plain load (SSA redef,
//     no copy, no conditional live range). Tail refills clamp to elast ->
//     L1 hits on one hot row; p=0 predication keeps the math correct.
//   - Consumption distance = 2 compute phases (~200+ cyc latency cover).
// ---------------------------------------------------------------------------
__global__ __launch_bounds__(256, 4) void gat_gather_h4(
        const __half* __restrict__ xl, const __half* __restrict__ xr,
        const float* __restrict__ att, const float* __restrict__ bias,
        const int* __restrict__ row_off, const int* __restrict__ esrc,
        __half* __restrict__ out, int n) {
    const float LOG2E = 1.44269504f;
    int wave = threadIdx.x >> 6;
    int lane = threadIdx.x & 63;
    int node = blockIdx.x * 4 + wave;
    if (node >= n) return;
    int eslot = lane >> 4;        // 0..3 : which edge of the phase
    unsigned j = lane & 15;       // channels 16j .. 16j+15

    const uint4* xl16 = (const uint4*)xl;   // 32 uint4 per row
    unsigned jo = 2u * j;

    f16x2 xrv[8];
    *(uint4*)(&xrv[0]) = ((const uint4*)xr)[((unsigned)node << 5) + jo];
    *(uint4*)(&xrv[4]) = ((const uint4*)xr)[((unsigned)node << 5) + jo + 1];

    float4 a0 = *(const float4*)(att + j * 16);
    float4 a1 = *(const float4*)(att + j * 16 + 4);
    float4 a2 = *(const float4*)(att + j * 16 + 8);
    float4 a3 = *(const float4*)(att + j * 16 + 12);
    f16x2 atv[8] = {
        {(_Float16)(a0.x * LOG2E), (_Float16)(a0.y * LOG2E)},
        {(_Float16)(a0.z * LOG2E), (_Float16)(a0.w * LOG2E)},
        {(_Float16)(a1.x * LOG2E), (_Float16)(a1.y * LOG2E)},
        {(_Float16)(a1.z * LOG2E), (_Float16)(a1.w * LOG2E)},
        {(_Float16)(a2.x * LOG2E), (_Float16)(a2.y * LOG2E)},
        {(_Float16)(a2.z * LOG2E), (_Float16)(a2.w * LOG2E)},
        {(_Float16)(a3.x * LOG2E), (_Float16)(a3.y * LOG2E)},
        {(_Float16)(a3.z * LOG2E), (_Float16)(a3.w * LOG2E)}};
    const f16x2 k02 = {(_Float16)0.2f, (_Float16)0.2f};

    float acc[16] = {};
    float L = 0.f;

    int e0 = row_off[node], e1 = row_off[node + 1];
    int elast = (e1 > e0) ? e1 - 1 : 0;

    // prologue: srcs + 6 gathers for edges e0 .. e0+11
    int sA = esrc[min(e0 + 0 + eslot, elast)];
    int sB = esrc[min(e0 + 4 + eslot, elast)];
    int sC = esrc[min(e0 + 8 + eslot, elast)];
    uint4 A0 = xl16[((unsigned)sA << 5) + jo], A1 = xl16[((unsigned)sA << 5) + jo + 1];
    uint4 B0 = xl16[((unsigned)sB << 5) + jo], B1 = xl16[((unsigned)sB << 5) + jo + 1];
    uint4 C0 = xl16[((unsigned)sC << 5) + jo], C1 = xl16[((unsigned)sC << 5) + jo + 1];

#define H4_PHASE(R0, R1, EB)                                                  \
    {                                                                         \
        f16x2 v[8];                                                           \
        *(uint4*)(&v[0]) = R0;                                                \
        *(uint4*)(&v[4]) = R1;                                                \
        float t0 = 0.f, t1 = 0.f;                                             \
        _Pragma("unroll")                                                     \
        for (int k = 0; k < 4; ++k) {                                         \
            f16x2 sa = v[k] + xrv[k];                                         \
            f16x2 ra = __builtin_elementwise_max(sa, sa * k02);               \
            t0 = __builtin_amdgcn_fdot2(ra, atv[k], t0, false);               \
            f16x2 sb = v[k + 4] + xrv[k + 4];                                 \
            f16x2 rb = __builtin_elementwise_max(sb, sb * k02);               \
            t1 = __builtin_amdgcn_fdot2(rb, atv[k + 4], t1, false);           \
        }                                                                     \
        float t = t0 + t1;                                                    \
        t = dpp_add_f32<0xB1>(t);                                             \
        t = dpp_add_f32<0x4E>(t);                                             \
        float p = exp2f(t);                                                   \
        p = ((EB) + eslot < e1) ? p : 0.f;                                    \
        L += p;                                                               \
        _Pragma("unroll")                                                     \
        for (int k = 0; k < 8; ++k) {                                         \
            acc[2 * k]     = fmaf((float)v[k].x, p, acc[2 * k]);              \
            acc[2 * k + 1] = fmaf((float)v[k].y, p, acc[2 * k + 1]);          \
        }                                                                     \
    }

    for (int e = e0; e < e1; e += 12) {
        int nsA = esrc[min(e + 12 + eslot, elast)];
        int nsB = esrc[min(e + 16 + eslot, elast)];
        int nsC = esrc[min(e + 20 + eslot, elast)];
        H4_PHASE(A0, A1, e)
        A0 = xl16[((unsigned)nsA << 5) + jo];
        A1 = xl16[((unsigned)nsA << 5) + jo + 1];
        H4_PHASE(B0, B1, e + 4)
        B0 = xl16[((unsigned)nsB << 5) + jo];
        B1 = xl16[((unsigned)nsB << 5) + jo + 1];
        H4_PHASE(C0, C1, e + 8)
        C0 = xl16[((unsigned)nsC << 5) + jo];
        C1 = xl16[((unsigned)nsC << 5) + jo + 1];
    }
#undef H4_PHASE

    // reduce partial sums across the 4 edge-slots (once per node)
#pragma unroll
    for (int k = 0; k < 16; ++k) {
        acc[k] += __shfl_xor(acc[k], 16);
        acc[k] += __shfl_xor(acc[k], 32);
    }
    L += __shfl_xor(L, 16);
    L += __shfl_xor(L, 32);

    if (eslot == 0) {
        float inv = 1.f / (L + 1e-16f);
        float4 b0 = *(const float4*)(bias + j * 16);
        float4 b1v = *(const float4*)(bias + j * 16 + 4);
        float4 b2v = *(const float4*)(bias + j * 16 + 8);
        float4 b3v = *(const float4*)(bias + j * 16 + 12);
        float bb[16] = {b0.x,  b0.y,  b0.z,  b0.w,  b1v.x, b1v.y, b1v.z, b1v.w,
                        b2v.x, b2v.y, b2v.z, b2v.w, b3v.x, b3v.y, b3v.z, b3v.w};
        f16x8 o0, o1;
#pragma unroll
        for (int k = 0; k < 8; ++k) {
            float vA = acc[k] * inv + bb[k];
            vA = vA > 0.f ? vA : __expf(vA) - 1.f;   // ELU
            o0[k] = (_Float16)vA;
            float vB = acc[k + 8] * inv + bb[k + 8];
            vB = vB > 0.f ? vB : __expf(vB) - 1.f;
            o1[k] = (_Float16)vB;
        }
        _Float16* op = (_Float16*)out + ((size_t)node << 8) + j * 16;
        *(f16x8*)op = o0;
        *(f16x8*)(op + 8) = o1;
    }
}

// ---------------------------------------------------------------------------
// GATv2 gather, H=1 x C=64 (no ELU). 8 lanes/edge x 8 slots, same 3-buffer
// copy-free rotation with unconditional clamped refills (24 edges/iter).
// ---------------------------------------------------------------------------
__global__ __launch_bounds__(256, 4) void gat_gather_h1(
        const __half* __restrict__ xl, const __half* __restrict__ xr,
        const float* __restrict__ att, const float* __restrict__ bias,
        const int* __restrict__ row_off, const int* __restrict__ esrc,
        __half* __restrict__ out, int n) {
    const float LOG2E = 1.44269504f;
    int wave = threadIdx.x >> 6;
    int lane = threadIdx.x & 63;
    int node = blockIdx.x * 4 + wave;
    if (node >= n) return;
    int eslot = lane >> 3;        // 0..7
    unsigned j = lane & 7;        // channels 8j .. 8j+7

    const uint4* xl16 = (const uint4*)xl;   // 8 uint4 per row

    f16x2 xrv[4];
    *(uint4*)(&xrv[0]) = ((const uint4*)xr)[((unsigned)node << 3) + j];

    float4 a0 = *(const float4*)(att + j * 8);
    float4 a1 = *(const float4*)(att + j * 8 + 4);
    f16x2 atv[4] = {
        {(_Float16)(a0.x * LOG2E), (_Float16)(a0.y * LOG2E)},
        {(_Float16)(a0.z * LOG2E), (_Float16)(a0.w * LOG2E)},
        {(_Float16)(a1.x * LOG2E), (_Float16)(a1.y * LOG2E)},
        {(_Float16)(a1.z * LOG2E), (_Float16)(a1.w * LOG2E)}};
    const f16x2 k02 = {(_Float16)0.2f, (_Float16)0.2f};

    float acc[8] = {};
    float L = 0.f;

    int e0 = row_off[node], e1 = row_off[node + 1];
    int elast = (e1 > e0) ? e1 - 1 : 0;

    // prologue: srcs + 3 gathers for edges e0 .. e0+23
    int sA = esrc[min(e0 +  0 + eslot, elast)];
    int sB = esrc[min(e0 +  8 + eslot, elast)];
    int sC = esrc[min(e0 + 16 + eslot, elast)];
    uint4 A = xl16[((unsigned)sA << 3) + j];
    uint4 B = xl16[((unsigned)sB << 3) + j];
    uint4 C = xl16[((unsigned)sC << 3) + j];

#define H1_PHASE(R, EB)                                                       \
    {                                                                         \
        f16x2 v[4];                                                           \
        *(uint4*)(&v[0]) = R;                                                 \
        float t0 = 0.f, t1 = 0.f;                                             \
        {                                                                     \
            f16x2 s0 = v[0] + xrv[0];                                         \
            f16x2 r0 = __builtin_elementwise_max(s0, s0 * k02);               \
            t0 = __builtin_amdgcn_fdot2(r0, atv[0], t0, false);               \
            f16x2 s1 = v[1] + xrv[1];                                         \
            f16x2 r1 = __builtin_elementwise_max(s1, s1 * k02);               \
            t0 = __builtin_amdgcn_fdot2(r1, atv[1], t0, false);               \
            f16x2 s2 = v[2] + xrv[2];                                         \
            f16x2 r2 = __builtin_elementwise_max(s2, s2 * k02);               \
            t1 = __builtin_amdgcn_fdot2(r2, atv[2], t1, false);               \
            f16x2 s3 = v[3] + xrv[3];                                         \
            f16x2 r3 = __builtin_elementwise_max(s3, s3 * k02);               \
            t1 = __builtin_amdgcn_fdot2(r3, atv[3], t1, false);               \
        }                                                                     \
        float t = t0 + t1;                                                    \
        t = dpp_add_f32<0xB1>(t);                                             \
        t = dpp_add_f32<0x4E>(t);                                             \
        t = dpp_add_f32<0x141>(t);                                            \
        float p = exp2f(t);                                                   \
        p = ((EB) + eslot < e1) ? p : 0.f;                                    \
        L += p;                                                               \
        _Pragma("unroll")                                                     \
        for (int k = 0; k < 4; ++k) {                                         \
            acc[2 * k]     = fmaf((float)v[k].x, p, acc[2 * k]);              \
            acc[2 * k + 1] = fmaf((float)v[k].y, p, acc[2 * k + 1]);          \
        }                                                                     \
    }

    for (int e = e0; e < e1; e += 24) {
        int nsA = esrc[min(e + 24 + eslot, elast)];
        int nsB = esrc[min(e + 32 + eslot, elast)];
        int nsC = esrc[min(e + 40 + eslot, elast)];
        H1_PHASE(A, e)
        A = xl16[((unsigned)nsA << 3) + j];
        H1_PHASE(B, e + 8)
        B = xl16[((unsigned)nsB << 3) + j];
        H1_PHASE(C, e + 16)
        C = xl16[((unsigned)nsC << 3) + j];
    }
#undef H1_PHASE

    // reduce partial sums across the 8 edge-slots
#pragma unroll
    for (int k = 0; k < 8; ++k) {
        acc[k] += __shfl_xor(acc[k], 8);
        acc[k] += __shfl_xor(acc[k], 16);
        acc[k] += __shfl_xor(acc[k], 32);
    }
    L += __shfl_xor(L, 8);
    L += __shfl_xor(L, 16);
    L += __shfl_xor(L, 32);

    if (eslot == 0) {
        float inv = 1.f / (L + 1e-16f);
        float4 b0 = *(const float4*)(bias + j * 8);
        float4 b1v = *(const float4*)(bias + j * 8 + 4);
        float bb[8] = {b0.x, b0.y, b0.z, b0.w, b1v.x, b1v.y, b1v.z, b1v.w};
        f16x8 ov;
#pragma unroll
        for (int k = 0; k < 8; ++k)
            ov[k] = (_Float16)(acc[k] * inv + bb[k]);
        *(f16x8*)((_Float16*)out + ((size_t)node << 6) + j * 8) = ov;
    }
}

// ---------------------------------------------------------------------------
extern "C" void kernel_launch(void* const* d_in, const int* in_sizes, int n_in,
                              void* d_out, int out_size, void* d_ws, size_t ws_size,
                              hipStream_t stream) {
    const float* x    = (const float*)d_in[0];
    const float* Wl1  = (const float*)d_in[1];
    const float* Wr1  = (const float*)d_in[2];
    const float* att1 = (const float*)d_in[3];
    const float* b1   = (const float*)d_in[4];
    const float* Wl2  = (const float*)d_in[5];
    const float* Wr2  = (const float*)d_in[6];
    const float* att2 = (const float*)d_in[7];
    const float* b2   = (const float*)d_in[8];
    const float* Wl3  = (const float*)d_in[9];
    const float* Wr3  = (const float*)d_in[10];
    const float* att3 = (const float*)d_in[11];
    const float* b3   = (const float*)d_in[12];
    const float* Wlin = (const float*)d_in[13];
    const float* blin = (const float*)d_in[14];
    const int*   ei   = (const int*)d_in[15];
    const int* src = ei;
    const int* dst = ei + EE;

    const int N = NN, E = EE;
    const int NB = (N + 255) / 256;             // 196 scan blocks

    __half* xf = (__half*)d_ws;                 // N*128
    __half* xl = xf + (size_t)N * 128;          // N*256
    __half* xr = xl + (size_t)N * 256;          // N*256
    __half* H  = xr + (size_t)N * 256;          // N*256
    __half* G  = H + (size_t)N * 256;           // N*64
    __half* w1 = G + (size_t)N * 64;            // 65536  frag-layout
    __half* w2 = w1 + 65536;                    // 131072
    __half* w3 = w2 + 131072;                   // 32768
    __half* w4 = w3 + 32768;                    // 4096
    int* row_off = (int*)(w4 + 4096);           // N+1
    int* tmp     = row_off + (N + 1);           // 2N (counts | cursor)
    int* esrc    = tmp + 2 * N;                 // E
    int* bsum    = esrc + E;                    // 256

    // --- build CSR by dst ---
    hipMemsetAsync(tmp, 0, (size_t)2 * N * sizeof(int), stream);
    hist_kernel<<<1024, 256, 0, stream>>>(dst, tmp, E);
    scan_phaseA<<<NB, 256, 0, stream>>>(tmp, bsum, N);
    scan_phaseB<<<1, 256, 0, stream>>>(bsum, row_off + N, NB);
    scan_phaseC<<<NB, 256, 0, stream>>>(tmp, bsum, row_off, N);
    scatter_kernel<<<1024, 256, 0, stream>>>(src, dst, row_off, tmp + N, esrc, E);

    // --- weights (fragment layout) + x -> fp16 ---
    int n4x = N * 128 / 4;
    prep_all<<<(233472 + n4x + 255) / 256, 256, 0, stream>>>(
        Wl1, Wr1, Wl2, Wr2, Wl3, Wr3, Wlin, w1, w2, w3, w4, x, xf, n4x);

    int nTiles = (N + 63) / 64;                 // 782
    int gatherBlocks = (N + 3) / 4;

    // --- layer 1: xf[128] @ w1 -> xl,xr fp16 ---
    gemm_ws<4, 2><<<dim3(128, 4), 512, 0, stream>>>(
        xf, w1, N, nTiles, 512, 256, xl, xr, nullptr, nullptr);
    gat_gather_h4<<<gatherBlocks, 256, 0, stream>>>(xl, xr, att1, b1, row_off, esrc, H, N);

    // --- layer 2: H[256] @ w2 -> xl,xr ---
    gemm_ws<8, 2><<<dim3(128, 4), 512, 0, stream>>>(
        H, w2, N, nTiles, 512, 256, xl, xr, nullptr, nullptr);
    gat_gather_h4<<<gatherBlocks, 256, 0, stream>>>(xl, xr, att2, b2, row_off, esrc, H, N);

    // --- layer 3: H[256] @ w3 -> xl,xr ([N][64] each) ---
    gemm_ws<8, 2><<<dim3(256, 1), 512, 0, stream>>>(
        H, w3, N, nTiles, 128, 64, xl, xr, nullptr, nullptr);
    gat_gather_h1<<<gatherBlocks, 256, 0, stream>>>(xl, xr, att3, b3, row_off, esrc, G, N);

    // --- final: G[64] @ w4 + blin -> d_out fp32 ---
    gemm_ws<2, 1><<<dim3(512, 1), 256, 0, stream>>>(
        G, w4, N, nTiles, 64, 64, nullptr, nullptr, (float*)d_out, blin);
}

// Round 4
// 463.053 us; speedup vs baseline: 1.1722x; 1.0313x over previous
//
#include <hip/hip_runtime.h>
#include <hip/hip_fp16.h>

#define NN 50000
#define EE 800000

typedef float f32x4 __attribute__((ext_vector_type(4)));
typedef _Float16 f16x8 __attribute__((ext_vector_type(8)));
typedef _Float16 f16x4 __attribute__((ext_vector_type(4)));
typedef _Float16 f16x2 __attribute__((ext_vector_type(2)));

// ---------------------------------------------------------------------------
// CSR build
// ---------------------------------------------------------------------------
__global__ void hist_kernel(const int* __restrict__ dst, int* __restrict__ counts, int E) {
    int idx = blockIdx.x * blockDim.x + threadIdx.x;
    int stride = gridDim.x * blockDim.x;
    for (int e = idx; e < E; e += stride)
        atomicAdd(&counts[dst[e]], 1);
}

__global__ void scan_phaseA(const int* __restrict__ counts, int* __restrict__ bsum, int n) {
    __shared__ int buf[256];
    int b = blockIdx.x, t = threadIdx.x;
    int i = b * 256 + t;
    buf[t] = (i < n) ? counts[i] : 0;
    __syncthreads();
#pragma unroll
    for (int off = 128; off; off >>= 1) {
        if (t < off) buf[t] += buf[t + off];
        __syncthreads();
    }
    if (t == 0) bsum[b] = buf[0];
}

__global__ void scan_phaseB(int* __restrict__ bsum, int* __restrict__ row_off_n, int nb) {
    __shared__ int buf[256];
    int t = threadIdx.x;
    int v = (t < nb) ? bsum[t] : 0;
    buf[t] = v;
    __syncthreads();
#pragma unroll
    for (int off = 1; off < 256; off <<= 1) {
        int x = (t >= off) ? buf[t - off] : 0;
        __syncthreads();
        buf[t] += x;
        __syncthreads();
    }
    if (t < nb) bsum[t] = buf[t] - v;       // exclusive block offset
    if (t == 255) *row_off_n = buf[255];    // total -> row_off[N]
}

__global__ void scan_phaseC(const int* __restrict__ counts, const int* __restrict__ bsum,
                            int* __restrict__ row_off, int n) {
    __shared__ int buf[256];
    int b = blockIdx.x, t = threadIdx.x;
    int i = b * 256 + t;
    int v = (i < n) ? counts[i] : 0;
    buf[t] = v;
    __syncthreads();
#pragma unroll
    for (int off = 1; off < 256; off <<= 1) {
        int x = (t >= off) ? buf[t - off] : 0;
        __syncthreads();
        buf[t] += x;
        __syncthreads();
    }
    if (i < n) row_off[i] = bsum[b] + buf[t] - v;
}

__global__ void scatter_kernel(const int* __restrict__ src, const int* __restrict__ dst,
                               const int* __restrict__ row_off, int* __restrict__ cursor,
                               int* __restrict__ esrc, int E) {
    int idx = blockIdx.x * blockDim.x + threadIdx.x;
    int stride = gridDim.x * blockDim.x;
    for (int e = idx; e < E; e += stride) {
        int d = dst[e];
        int pos = row_off[d] + atomicAdd(&cursor[d], 1);
        esrc[pos] = src[e];
    }
}

// ---------------------------------------------------------------------------
// Fused prep: weights -> FRAGMENT-READY fp16 layout, x -> fp16.
// ---------------------------------------------------------------------------
__device__ __forceinline__ void wfrag_store(__half* o, int K, int col, int k, float v) {
    int KS = K >> 5;
    int cgni = col >> 4, l15 = col & 15;
    int ks = k >> 5, qq = (k >> 3) & 3, ee = k & 7;
    size_t flat = ((size_t)(cgni * KS + ks) * 64 + qq * 16 + l15) * 8 + ee;
    o[flat] = __float2half_rn(v);
}

__global__ void prep_all(const float* __restrict__ Wl1, const float* __restrict__ Wr1,
                         const float* __restrict__ Wl2, const float* __restrict__ Wr2,
                         const float* __restrict__ Wl3, const float* __restrict__ Wr3,
                         const float* __restrict__ Wlin,
                         __half* __restrict__ w1, __half* __restrict__ w2,
                         __half* __restrict__ w3, __half* __restrict__ w4,
                         const float* __restrict__ x, __half* __restrict__ xf, int n4x) {
    int idx = blockIdx.x * blockDim.x + threadIdx.x;
    if (idx < 233472) {
        const float* W; __half* o; int K, Nc, roff, li;
        if (idx < 65536) {
            K = 128; Nc = 256; o = w1;
            if (idx < 32768) { W = Wl1; li = idx; roff = 0; }
            else             { W = Wr1; li = idx - 32768; roff = 256; }
        } else if (idx < 196608) {
            K = 256; Nc = 256; o = w2;
            if (idx < 131072) { W = Wl2; li = idx - 65536; roff = 0; }
            else              { W = Wr2; li = idx - 131072; roff = 256; }
        } else if (idx < 229376) {
            K = 256; Nc = 64; o = w3;
            if (idx < 212992) { W = Wl3; li = idx - 196608; roff = 0; }
            else              { W = Wr3; li = idx - 212992; roff = 64; }
        } else {
            K = 64; Nc = 64; o = w4; W = Wlin; li = idx - 229376; roff = 0;
        }
        int k = li / Nc, n = li - k * Nc;
        wfrag_store(o, K, roff + n, k, W[li]);
    } else {
        int xi = idx - 233472;
        if (xi < n4x) {
            float4 v = *(const float4*)(x + (size_t)xi * 4);
            f16x4 h = {(_Float16)v.x, (_Float16)v.y, (_Float16)v.z, (_Float16)v.w};
            *(f16x4*)((_Float16*)xf + (size_t)xi * 4) = h;
        }
    }
}

// ---------------------------------------------------------------------------
// Weight-stationary tall-skinny GEMM (unchanged).
// ---------------------------------------------------------------------------
template <int KS, int COLG>
__global__ __launch_bounds__(COLG * 256) void gemm_ws(
        const __half* __restrict__ A, const __half* __restrict__ Bt,
        int M, int nTiles, int Nc, int splitCol,
        __half* __restrict__ outL, __half* __restrict__ outR,
        float* __restrict__ outF, const float* __restrict__ bias) {
    constexpr int K = KS * 32;
    int tid = threadIdx.x;
    int lane = tid & 63;
    int w = tid >> 6;
    int rs = w & 3;
    int cg = w >> 2;
    int l15 = lane & 15, q = lane >> 4;
    int colbase = blockIdx.y * (COLG * 64) + cg * 64;

    const _Float16* Ap = (const _Float16*)A;
    const f16x8* Bf = (const f16x8*)Bt;
    int cgni0 = (blockIdx.y * COLG + cg) * 4;

    f16x8 bfrag[KS][4];
#pragma unroll
    for (int ks = 0; ks < KS; ++ks)
#pragma unroll
        for (int ni = 0; ni < 4; ++ni)
            bfrag[ks][ni] = Bf[((size_t)(cgni0 + ni) * KS + ks) * 64 + lane];

    int tile = blockIdx.x;
    if (tile >= nTiles) return;

    f16x8 afrag[KS];
    {
        int row = tile * 64 + rs * 16 + l15;
        if (row >= M) row = M - 1;
        const _Float16* ap = Ap + (size_t)row * K + q * 8;
#pragma unroll
        for (int ks = 0; ks < KS; ++ks) afrag[ks] = *(const f16x8*)(ap + ks * 32);
    }

    while (true) {
        int next = tile + gridDim.x;
        bool has = (next < nTiles);
        f16x8 anext[KS];
        if (has) {
            int row = next * 64 + rs * 16 + l15;
            if (row >= M) row = M - 1;
            const _Float16* ap = Ap + (size_t)row * K + q * 8;
#pragma unroll
            for (int ks = 0; ks < KS; ++ks) anext[ks] = *(const f16x8*)(ap + ks * 32);
        }

        f32x4 acc[4] = {};
#pragma unroll
        for (int ks = 0; ks < KS; ++ks)
#pragma unroll
            for (int ni = 0; ni < 4; ++ni)
                acc[ni] = __builtin_amdgcn_mfma_f32_16x16x32_f16(afrag[ks], bfrag[ks][ni], acc[ni], 0, 0, 0);

#pragma unroll
        for (int ni = 0; ni < 4; ++ni) {
            int gc = colbase + ni * 16 + l15;
            if (outF) {
                float bv = bias ? bias[gc] : 0.f;
#pragma unroll
                for (int r = 0; r < 4; ++r) {
                    int gr = tile * 64 + rs * 16 + q * 4 + r;
                    if (gr < M) outF[(size_t)gr * Nc + gc] = acc[ni][r] + bv;
                }
            } else {
                __half* dp = outL; int cc = gc;
                if (gc >= splitCol) { dp = outR; cc = gc - splitCol; }
#pragma unroll
                for (int r = 0; r < 4; ++r) {
                    int gr = tile * 64 + rs * 16 + q * 4 + r;
                    if (gr < M) dp[(size_t)gr * splitCol + cc] = __float2half_rn(acc[ni][r]);
                }
            }
        }
        if (!has) break;
#pragma unroll
        for (int ks = 0; ks < KS; ++ks) afrag[ks] = anext[ks];
        tile = next;
    }
}

// ---------------------------------------------------------------------------
// DPP helpers: butterfly adds on the VALU pipe.
//   0xB1 = quad_perm [1,0,3,2]  (xor 1)
//   0x4E = quad_perm [2,3,0,1]  (xor 2)
//   0x141 = row_half_mirror     (combines the two quads of an 8-lane group)
// ---------------------------------------------------------------------------
template <int CTRL>
__device__ __forceinline__ float dpp_add_f32(float x) {
    int y = __builtin_amdgcn_mov_dpp(__float_as_int(x), CTRL, 0xF, 0xF, true);
    return x + __int_as_float(y);
}

// ---------------------------------------------------------------------------
// GATv2 gather, H=4 x C=64. R15: 32 lanes/edge x 2 edge-slots per wave.
//   - each lane holds 8 channels (1 uint4/edge) -> acc = 8 f32, 4-deep buffer
//     rotation costs only 16 VGPR -> total ~56 VGPR -> 8 waves/SIMD AND
//     8 edges in flight per wave (R12: ~4-6 waves x 2-4 loads; R14 traded
//     occupancy for depth; this gets both).
//   - head h = 8-lane group -> score reduce = 3 DPP adds (xor1,xor2,mirror).
//   - per-phase (2-edge) wave-uniform early exit -> tail waste ~1 edge/node
//     (R14's 12-edge granularity wasted ~27% of VALU work).
//   - refills unconditional + clamp-addressed (spill-proof, R14 idiom);
//     no register copies (R12 lesson).
// ---------------------------------------------------------------------------
__global__ __launch_bounds__(256, 8) void gat_gather_h4(
        const __half* __restrict__ xl, const __half* __restrict__ xr,
        const float* __restrict__ att, const float* __restrict__ bias,
        const int* __restrict__ row_off, const int* __restrict__ esrc,
        __half* __restrict__ out, int n) {
    const float LOG2E = 1.44269504f;
    int wave = threadIdx.x >> 6;
    int lane = threadIdx.x & 63;
    int node = blockIdx.x * 4 + wave;
    if (node >= n) return;
    int slot = lane >> 5;         // 0..1 : which edge of the phase
    unsigned jj = lane & 31;      // channels 8*jj .. 8*jj+7

    const uint4* xl16 = (const uint4*)xl;   // 32 uint4 per row

    f16x2 xrv[4];
    *(uint4*)(&xrv[0]) = ((const uint4*)xr)[((unsigned)node << 5) + jj];

    float4 a0 = *(const float4*)(att + jj * 8);
    float4 a1 = *(const float4*)(att + jj * 8 + 4);
    f16x2 atv[4] = {
        {(_Float16)(a0.x * LOG2E), (_Float16)(a0.y * LOG2E)},
        {(_Float16)(a0.z * LOG2E), (_Float16)(a0.w * LOG2E)},
        {(_Float16)(a1.x * LOG2E), (_Float16)(a1.y * LOG2E)},
        {(_Float16)(a1.z * LOG2E), (_Float16)(a1.w * LOG2E)}};
    const f16x2 k02 = {(_Float16)0.2f, (_Float16)0.2f};

    float acc[8] = {};
    float L = 0.f;

    int e0 = row_off[node], e1 = row_off[node + 1];
    int elast = (e1 > e0) ? e1 - 1 : 0;

    // prologue: srcs + 4 gathers covering edges e0 .. e0+7
    int sA = esrc[min(e0 + 0 + slot, elast)];
    int sB = esrc[min(e0 + 2 + slot, elast)];
    int sC = esrc[min(e0 + 4 + slot, elast)];
    int sD = esrc[min(e0 + 6 + slot, elast)];
    uint4 A = xl16[((unsigned)sA << 5) + jj];
    uint4 B = xl16[((unsigned)sB << 5) + jj];
    uint4 C = xl16[((unsigned)sC << 5) + jj];
    uint4 D = xl16[((unsigned)sD << 5) + jj];

#define H4_PHASE(BUF, EB)                                                     \
    {                                                                         \
        f16x2 v[4];                                                           \
        *(uint4*)(&v[0]) = BUF;                                               \
        float t = 0.f;                                                        \
        _Pragma("unroll")                                                     \
        for (int k = 0; k < 4; ++k) {                                         \
            f16x2 s = v[k] + xrv[k];                                          \
            f16x2 r = __builtin_elementwise_max(s, s * k02);                  \
            t = __builtin_amdgcn_fdot2(r, atv[k], t, false);                  \
        }                                                                     \
        t = dpp_add_f32<0xB1>(t);                                             \
        t = dpp_add_f32<0x4E>(t);                                             \
        t = dpp_add_f32<0x141>(t);                                            \
        float p = exp2f(t);                                                   \
        p = ((EB) + slot < e1) ? p : 0.f;                                     \
        L += p;                                                               \
        _Pragma("unroll")                                                     \
        for (int k = 0; k < 4; ++k) {                                         \
            acc[2 * k]     = fmaf((float)v[k].x, p, acc[2 * k]);              \
            acc[2 * k + 1] = fmaf((float)v[k].y, p, acc[2 * k + 1]);          \
        }                                                                     \
    }

    {
        int e = e0;
        while (true) {
            int ns = esrc[min(e + 8 + slot, elast)];
            H4_PHASE(A, e)
            A = xl16[((unsigned)ns << 5) + jj];
            e += 2; if (e >= e1) break;
            ns = esrc[min(e + 8 + slot, elast)];
            H4_PHASE(B, e)
            B = xl16[((unsigned)ns << 5) + jj];
            e += 2; if (e >= e1) break;
            ns = esrc[min(e + 8 + slot, elast)];
            H4_PHASE(C, e)
            C = xl16[((unsigned)ns << 5) + jj];
            e += 2; if (e >= e1) break;
            ns = esrc[min(e + 8 + slot, elast)];
            H4_PHASE(D, e)
            D = xl16[((unsigned)ns << 5) + jj];
            e += 2; if (e >= e1) break;
        }
    }
#undef H4_PHASE

    // reduce partial sums across the 2 edge-slots (once per node)
#pragma unroll
    for (int k = 0; k < 8; ++k) acc[k] += __shfl_xor(acc[k], 32);
    L += __shfl_xor(L, 32);

    if (slot == 0) {
        float inv = 1.f / (L + 1e-16f);
        float4 b0 = *(const float4*)(bias + jj * 8);
        float4 b1v = *(const float4*)(bias + jj * 8 + 4);
        float bb[8] = {b0.x, b0.y, b0.z, b0.w, b1v.x, b1v.y, b1v.z, b1v.w};
        f16x8 o0;
#pragma unroll
        for (int k = 0; k < 8; ++k) {
            float vA = acc[k] * inv + bb[k];
            vA = vA > 0.f ? vA : __expf(vA) - 1.f;   // ELU
            o0[k] = (_Float16)vA;
        }
        *(f16x8*)((_Float16*)out + ((size_t)node << 8) + jj * 8) = o0;
    }
}

// ---------------------------------------------------------------------------
// GATv2 gather, H=1 x C=64 (no ELU). 8 lanes/edge x 8 slots, 3-buffer
// copy-free rotation with unconditional clamped refills + per-phase early
// exit (step 8: deg-16 nodes do exactly 2 phases, zero tail waste).
// ---------------------------------------------------------------------------
__global__ __launch_bounds__(256, 8) void gat_gather_h1(
        const __half* __restrict__ xl, const __half* __restrict__ xr,
        const float* __restrict__ att, const float* __restrict__ bias,
        const int* __restrict__ row_off, const int* __restrict__ esrc,
        __half* __restrict__ out, int n) {
    const float LOG2E = 1.44269504f;
    int wave = threadIdx.x >> 6;
    int lane = threadIdx.x & 63;
    int node = blockIdx.x * 4 + wave;
    if (node >= n) return;
    int eslot = lane >> 3;        // 0..7
    unsigned j = lane & 7;        // channels 8j .. 8j+7

    const uint4* xl16 = (const uint4*)xl;   // 8 uint4 per row

    f16x2 xrv[4];
    *(uint4*)(&xrv[0]) = ((const uint4*)xr)[((unsigned)node << 3) + j];

    float4 a0 = *(const float4*)(att + j * 8);
    float4 a1 = *(const float4*)(att + j * 8 + 4);
    f16x2 atv[4] = {
        {(_Float16)(a0.x * LOG2E), (_Float16)(a0.y * LOG2E)},
        {(_Float16)(a0.z * LOG2E), (_Float16)(a0.w * LOG2E)},
        {(_Float16)(a1.x * LOG2E), (_Float16)(a1.y * LOG2E)},
        {(_Float16)(a1.z * LOG2E), (_Float16)(a1.w * LOG2E)}};
    const f16x2 k02 = {(_Float16)0.2f, (_Float16)0.2f};

    float acc[8] = {};
    float L = 0.f;

    int e0 = row_off[node], e1 = row_off[node + 1];
    int elast = (e1 > e0) ? e1 - 1 : 0;

    // prologue: srcs + 3 gathers for edges e0 .. e0+23
    int sA = esrc[min(e0 +  0 + eslot, elast)];
    int sB = esrc[min(e0 +  8 + eslot, elast)];
    int sC = esrc[min(e0 + 16 + eslot, elast)];
    uint4 A = xl16[((unsigned)sA << 3) + j];
    uint4 B = xl16[((unsigned)sB << 3) + j];
    uint4 C = xl16[((unsigned)sC << 3) + j];

#define H1_PHASE(R, EB)                                                       \
    {                                                                         \
        f16x2 v[4];                                                           \
        *(uint4*)(&v[0]) = R;                                                 \
        float t0 = 0.f, t1 = 0.f;                                             \
        {                                                                     \
            f16x2 s0 = v[0] + xrv[0];                                         \
            f16x2 r0 = __builtin_elementwise_max(s0, s0 * k02);               \
            t0 = __builtin_amdgcn_fdot2(r0, atv[0], t0, false);               \
            f16x2 s1 = v[1] + xrv[1];                                         \
            f16x2 r1 = __builtin_elementwise_max(s1, s1 * k02);               \
            t0 = __builtin_amdgcn_fdot2(r1, atv[1], t0, false);               \
            f16x2 s2 = v[2] + xrv[2];                                         \
            f16x2 r2 = __builtin_elementwise_max(s2, s2 * k02);               \
            t1 = __builtin_amdgcn_fdot2(r2, atv[2], t1, false);               \
            f16x2 s3 = v[3] + xrv[3];                                         \
            f16x2 r3 = __builtin_elementwise_max(s3, s3 * k02);               \
            t1 = __builtin_amdgcn_fdot2(r3, atv[3], t1, false);               \
        }                                                                     \
        float t = t0 + t1;                                                    \
        t = dpp_add_f32<0xB1>(t);                                             \
        t = dpp_add_f32<0x4E>(t);                                             \
        t = dpp_add_f32<0x141>(t);                                            \
        float p = exp2f(t);                                                   \
        p = ((EB) + eslot < e1) ? p : 0.f;                                    \
        L += p;                                                               \
        _Pragma("unroll")                                                     \
        for (int k = 0; k < 4; ++k) {                                         \
            acc[2 * k]     = fmaf((float)v[k].x, p, acc[2 * k]);              \
            acc[2 * k + 1] = fmaf((float)v[k].y, p, acc[2 * k + 1]);          \
        }                                                                     \
    }

    {
        int e = e0;
        while (true) {
            int ns = esrc[min(e + 24 + eslot, elast)];
            H1_PHASE(A, e)
            A = xl16[((unsigned)ns << 3) + j];
            e += 8; if (e >= e1) break;
            ns = esrc[min(e + 24 + eslot, elast)];
            H1_PHASE(B, e)
            B = xl16[((unsigned)ns << 3) + j];
            e += 8; if (e >= e1) break;
            ns = esrc[min(e + 24 + eslot, elast)];
            H1_PHASE(C, e)
            C = xl16[((unsigned)ns << 3) + j];
            e += 8; if (e >= e1) break;
        }
    }
#undef H1_PHASE

    // reduce partial sums across the 8 edge-slots
#pragma unroll
    for (int k = 0; k < 8; ++k) {
        acc[k] += __shfl_xor(acc[k], 8);
        acc[k] += __shfl_xor(acc[k], 16);
        acc[k] += __shfl_xor(acc[k], 32);
    }
    L += __shfl_xor(L, 8);
    L += __shfl_xor(L, 16);
    L += __shfl_xor(L, 32);

    if (eslot == 0) {
        float inv = 1.f / (L + 1e-16f);
        float4 b0 = *(const float4*)(bias + j * 8);
        float4 b1v = *(const float4*)(bias + j * 8 + 4);
        float bb[8] = {b0.x, b0.y, b0.z, b0.w, b1v.x, b1v.y, b1v.z, b1v.w};
        f16x8 ov;
#pragma unroll
        for (int k = 0; k < 8; ++k)
            ov[k] = (_Float16)(acc[k] * inv + bb[k]);
        *(f16x8*)((_Float16*)out + ((size_t)node << 6) + j * 8) = ov;
    }
}

// ---------------------------------------------------------------------------
extern "C" void kernel_launch(void* const* d_in, const int* in_sizes, int n_in,
                              void* d_out, int out_size, void* d_ws, size_t ws_size,
                              hipStream_t stream) {
    const float* x    = (const float*)d_in[0];
    const float* Wl1  = (const float*)d_in[1];
    const float* Wr1  = (const float*)d_in[2];
    const float* att1 = (const float*)d_in[3];
    const float* b1   = (const float*)d_in[4];
    const float* Wl2  = (const float*)d_in[5];
    const float* Wr2  = (const float*)d_in[6];
    const float* att2 = (const float*)d_in[7];
    const float* b2   = (const float*)d_in[8];
    const float* Wl3  = (const float*)d_in[9];
    const float* Wr3  = (const float*)d_in[10];
    const float* att3 = (const float*)d_in[11];
    const float* b3   = (const float*)d_in[12];
    const float* Wlin = (const float*)d_in[13];
    const float* blin = (const float*)d_in[14];
    const int*   ei   = (const int*)d_in[15];
    const int* src = ei;
    const int* dst = ei + EE;

    const int N = NN, E = EE;
    const int NB = (N + 255) / 256;             // 196 scan blocks

    __half* xf = (__half*)d_ws;                 // N*128
    __half* xl = xf + (size_t)N * 128;          // N*256
    __half* xr = xl + (size_t)N * 256;          // N*256
    __half* H  = xr + (size_t)N * 256;          // N*256
    __half* G  = H + (size_t)N * 256;           // N*64
    __half* w1 = G + (size_t)N * 64;            // 65536  frag-layout
    __half* w2 = w1 + 65536;                    // 131072
    __half* w3 = w2 + 131072;                   // 32768
    __half* w4 = w3 + 32768;                    // 4096
    int* row_off = (int*)(w4 + 4096);           // N+1
    int* tmp     = row_off + (N + 1);           // 2N (counts | cursor)
    int* esrc    = tmp + 2 * N;                 // E
    int* bsum    = esrc + E;                    // 256

    // --- build CSR by dst ---
    hipMemsetAsync(tmp, 0, (size_t)2 * N * sizeof(int), stream);
    hist_kernel<<<1024, 256, 0, stream>>>(dst, tmp, E);
    scan_phaseA<<<NB, 256, 0, stream>>>(tmp, bsum, N);
    scan_phaseB<<<1, 256, 0, stream>>>(bsum, row_off + N, NB);
    scan_phaseC<<<NB, 256, 0, stream>>>(tmp, bsum, row_off, N);
    scatter_kernel<<<1024, 256, 0, stream>>>(src, dst, row_off, tmp + N, esrc, E);

    // --- weights (fragment layout) + x -> fp16 ---
    int n4x = N * 128 / 4;
    prep_all<<<(233472 + n4x + 255) / 256, 256, 0, stream>>>(
        Wl1, Wr1, Wl2, Wr2, Wl3, Wr3, Wlin, w1, w2, w3, w4, x, xf, n4x);

    int nTiles = (N + 63) / 64;                 // 782
    int gatherBlocks = (N + 3) / 4;

    // --- layer 1: xf[128] @ w1 -> xl,xr fp16 ---
    gemm_ws<4, 2><<<dim3(128, 4), 512, 0, stream>>>(
        xf, w1, N, nTiles, 512, 256, xl, xr, nullptr, nullptr);
    gat_gather_h4<<<gatherBlocks, 256, 0, stream>>>(xl, xr, att1, b1, row_off, esrc, H, N);

    // --- layer 2: H[256] @ w2 -> xl,xr ---
    gemm_ws<8, 2><<<dim3(128, 4), 512, 0, stream>>>(
        H, w2, N, nTiles, 512, 256, xl, xr, nullptr, nullptr);
    gat_gather_h4<<<gatherBlocks, 256, 0, stream>>>(xl, xr, att2, b2, row_off, esrc, H, N);

    // --- layer 3: H[256] @ w3 -> xl,xr ([N][64] each) ---
    gemm_ws<8, 2><<<dim3(256, 1), 512, 0, stream>>>(
        H, w3, N, nTiles, 128, 64, xl, xr, nullptr, nullptr);
    gat_gather_h1<<<gatherBlocks, 256, 0, stream>>>(xl, xr, att3, b3, row_off, esrc, G, N);

    // --- final: G[64] @ w4 + blin -> d_out fp32 ---
    gemm_ws<2, 1><<<dim3(512, 1), 256, 0, stream>>>(
        G, w4, N, nTiles, 64, 64, nullptr, nullptr, (float*)d_out, blin);
}

// Round 5
// 460.414 us; speedup vs baseline: 1.1789x; 1.0057x over previous
//
#include <hip/hip_runtime.h>
#include <hip/hip_fp16.h>

#define NN 50000
#define EE 800000

typedef float f32x4 __attribute__((ext_vector_type(4)));
typedef _Float16 f16x8 __attribute__((ext_vector_type(8)));
typedef _Float16 f16x4 __attribute__((ext_vector_type(4)));
typedef _Float16 f16x2 __attribute__((ext_vector_type(2)));

// ---------------------------------------------------------------------------
// CSR build
// ---------------------------------------------------------------------------
__global__ void hist_kernel(const int* __restrict__ dst, int* __restrict__ counts, int E) {
    int idx = blockIdx.x * blockDim.x + threadIdx.x;
    int stride = gridDim.x * blockDim.x;
    for (int e = idx; e < E; e += stride)
        atomicAdd(&counts[dst[e]], 1);
}

__global__ void scan_phaseA(const int* __restrict__ counts, int* __restrict__ bsum, int n) {
    __shared__ int buf[256];
    int b = blockIdx.x, t = threadIdx.x;
    int i = b * 256 + t;
    buf[t] = (i < n) ? counts[i] : 0;
    __syncthreads();
#pragma unroll
    for (int off = 128; off; off >>= 1) {
        if (t < off) buf[t] += buf[t + off];
        __syncthreads();
    }
    if (t == 0) bsum[b] = buf[0];
}

__global__ void scan_phaseB(int* __restrict__ bsum, int* __restrict__ row_off_n, int nb) {
    __shared__ int buf[256];
    int t = threadIdx.x;
    int v = (t < nb) ? bsum[t] : 0;
    buf[t] = v;
    __syncthreads();
#pragma unroll
    for (int off = 1; off < 256; off <<= 1) {
        int x = (t >= off) ? buf[t - off] : 0;
        __syncthreads();
        buf[t] += x;
        __syncthreads();
    }
    if (t < nb) bsum[t] = buf[t] - v;       // exclusive block offset
    if (t == 255) *row_off_n = buf[255];    // total -> row_off[N]
}

__global__ void scan_phaseC(const int* __restrict__ counts, const int* __restrict__ bsum,
                            int* __restrict__ row_off, int n) {
    __shared__ int buf[256];
    int b = blockIdx.x, t = threadIdx.x;
    int i = b * 256 + t;
    int v = (i < n) ? counts[i] : 0;
    buf[t] = v;
    __syncthreads();
#pragma unroll
    for (int off = 1; off < 256; off <<= 1) {
        int x = (t >= off) ? buf[t - off] : 0;
        __syncthreads();
        buf[t] += x;
        __syncthreads();
    }
    if (i < n) row_off[i] = bsum[b] + buf[t] - v;
}

__global__ void scatter_kernel(const int* __restrict__ src, const int* __restrict__ dst,
                               const int* __restrict__ row_off, int* __restrict__ cursor,
                               int* __restrict__ esrc, int E) {
    int idx = blockIdx.x * blockDim.x + threadIdx.x;
    int stride = gridDim.x * blockDim.x;
    for (int e = idx; e < E; e += stride) {
        int d = dst[e];
        int pos = row_off[d] + atomicAdd(&cursor[d], 1);
        esrc[pos] = src[e];
    }
}

// ---------------------------------------------------------------------------
// Fused prep: weights -> FRAGMENT-READY fp16 layout, x -> fp16.
// ---------------------------------------------------------------------------
__device__ __forceinline__ void wfrag_store(__half* o, int K, int col, int k, float v) {
    int KS = K >> 5;
    int cgni = col >> 4, l15 = col & 15;
    int ks = k >> 5, qq = (k >> 3) & 3, ee = k & 7;
    size_t flat = ((size_t)(cgni * KS + ks) * 64 + qq * 16 + l15) * 8 + ee;
    o[flat] = __float2half_rn(v);
}

__global__ void prep_all(const float* __restrict__ Wl1, const float* __restrict__ Wr1,
                         const float* __restrict__ Wl2, const float* __restrict__ Wr2,
                         const float* __restrict__ Wl3, const float* __restrict__ Wr3,
                         const float* __restrict__ Wlin,
                         __half* __restrict__ w1, __half* __restrict__ w2,
                         __half* __restrict__ w3, __half* __restrict__ w4,
                         const float* __restrict__ x, __half* __restrict__ xf, int n4x) {
    int idx = blockIdx.x * blockDim.x + threadIdx.x;
    if (idx < 233472) {
        const float* W; __half* o; int K, Nc, roff, li;
        if (idx < 65536) {
            K = 128; Nc = 256; o = w1;
            if (idx < 32768) { W = Wl1; li = idx; roff = 0; }
            else             { W = Wr1; li = idx - 32768; roff = 256; }
        } else if (idx < 196608) {
            K = 256; Nc = 256; o = w2;
            if (idx < 131072) { W = Wl2; li = idx - 65536; roff = 0; }
            else              { W = Wr2; li = idx - 131072; roff = 256; }
        } else if (idx < 229376) {
            K = 256; Nc = 64; o = w3;
            if (idx < 212992) { W = Wl3; li = idx - 196608; roff = 0; }
            else              { W = Wr3; li = idx - 212992; roff = 64; }
        } else {
            K = 64; Nc = 64; o = w4; W = Wlin; li = idx - 229376; roff = 0;
        }
        int k = li / Nc, n = li - k * Nc;
        wfrag_store(o, K, roff + n, k, W[li]);
    } else {
        int xi = idx - 233472;
        if (xi < n4x) {
            float4 v = *(const float4*)(x + (size_t)xi * 4);
            f16x4 h = {(_Float16)v.x, (_Float16)v.y, (_Float16)v.z, (_Float16)v.w};
            *(f16x4*)((_Float16*)xf + (size_t)xi * 4) = h;
        }
    }
}

// ---------------------------------------------------------------------------
// Weight-stationary tall-skinny GEMM (unchanged).
// ---------------------------------------------------------------------------
template <int KS, int COLG>
__global__ __launch_bounds__(COLG * 256) void gemm_ws(
        const __half* __restrict__ A, const __half* __restrict__ Bt,
        int M, int nTiles, int Nc, int splitCol,
        __half* __restrict__ outL, __half* __restrict__ outR,
        float* __restrict__ outF, const float* __restrict__ bias) {
    constexpr int K = KS * 32;
    int tid = threadIdx.x;
    int lane = tid & 63;
    int w = tid >> 6;
    int rs = w & 3;
    int cg = w >> 2;
    int l15 = lane & 15, q = lane >> 4;
    int colbase = blockIdx.y * (COLG * 64) + cg * 64;

    const _Float16* Ap = (const _Float16*)A;
    const f16x8* Bf = (const f16x8*)Bt;
    int cgni0 = (blockIdx.y * COLG + cg) * 4;

    f16x8 bfrag[KS][4];
#pragma unroll
    for (int ks = 0; ks < KS; ++ks)
#pragma unroll
        for (int ni = 0; ni < 4; ++ni)
            bfrag[ks][ni] = Bf[((size_t)(cgni0 + ni) * KS + ks) * 64 + lane];

    int tile = blockIdx.x;
    if (tile >= nTiles) return;

    f16x8 afrag[KS];
    {
        int row = tile * 64 + rs * 16 + l15;
        if (row >= M) row = M - 1;
        const _Float16* ap = Ap + (size_t)row * K + q * 8;
#pragma unroll
        for (int ks = 0; ks < KS; ++ks) afrag[ks] = *(const f16x8*)(ap + ks * 32);
    }

    while (true) {
        int next = tile + gridDim.x;
        bool has = (next < nTiles);
        f16x8 anext[KS];
        if (has) {
            int row = next * 64 + rs * 16 + l15;
            if (row >= M) row = M - 1;
            const _Float16* ap = Ap + (size_t)row * K + q * 8;
#pragma unroll
            for (int ks = 0; ks < KS; ++ks) anext[ks] = *(const f16x8*)(ap + ks * 32);
        }

        f32x4 acc[4] = {};
#pragma unroll
        for (int ks = 0; ks < KS; ++ks)
#pragma unroll
            for (int ni = 0; ni < 4; ++ni)
                acc[ni] = __builtin_amdgcn_mfma_f32_16x16x32_f16(afrag[ks], bfrag[ks][ni], acc[ni], 0, 0, 0);

#pragma unroll
        for (int ni = 0; ni < 4; ++ni) {
            int gc = colbase + ni * 16 + l15;
            if (outF) {
                float bv = bias ? bias[gc] : 0.f;
#pragma unroll
                for (int r = 0; r < 4; ++r) {
                    int gr = tile * 64 + rs * 16 + q * 4 + r;
                    if (gr < M) outF[(size_t)gr * Nc + gc] = acc[ni][r] + bv;
                }
            } else {
                __half* dp = outL; int cc = gc;
                if (gc >= splitCol) { dp = outR; cc = gc - splitCol; }
#pragma unroll
                for (int r = 0; r < 4; ++r) {
                    int gr = tile * 64 + rs * 16 + q * 4 + r;
                    if (gr < M) dp[(size_t)gr * splitCol + cc] = __float2half_rn(acc[ni][r]);
                }
            }
        }
        if (!has) break;
#pragma unroll
        for (int ks = 0; ks < KS; ++ks) afrag[ks] = anext[ks];
        tile = next;
    }
}

// ---------------------------------------------------------------------------
// DPP helpers: butterfly adds on the VALU pipe.
//   0xB1 = quad_perm [1,0,3,2]  (xor 1)
//   0x4E = quad_perm [2,3,0,1]  (xor 2)
//   0x141 = row_half_mirror     (combines the two quads of an 8-lane group)
// ---------------------------------------------------------------------------
template <int CTRL>
__device__ __forceinline__ float dpp_add_f32(float x) {
    int y = __builtin_amdgcn_mov_dpp(__float_as_int(x), CTRL, 0xF, 0xF, true);
    return x + __int_as_float(y);
}

// raw v_exp_f32 (= 2^x), with s_nop hazard guard for the trans-op result
__device__ __forceinline__ float fast_exp2(float x) {
    float r;
    asm("v_exp_f32 %0, %1\n\ts_nop 0" : "=v"(r) : "v"(x));
    return r;
}

// ---------------------------------------------------------------------------
// GATv2 gather, H=4 x C=64. R16: 32 lanes/edge x 2 slots, 6-deep copy-free
// rotation, 512-thread blocks (8 nodes/block).
//   - R15 analysis: dur*VALUBusy == computed VALU work (45us) -> VALU-bound.
//     Occupancy 67% with VGPR=32/LDS=0 -> workgroup-slot packing suspected:
//     256-thr blocks need 8 blocks/CU for 32 waves; 512-thr blocks need 4.
//   - 6 buffers (24 VGPR) = 12 edges in flight; refills unconditional +
//     clamp-addressed (spill-proof); per-2-edge early exit (no tail waste).
// ---------------------------------------------------------------------------
__global__ __launch_bounds__(512, 8) void gat_gather_h4(
        const __half* __restrict__ xl, const __half* __restrict__ xr,
        const float* __restrict__ att, const float* __restrict__ bias,
        const int* __restrict__ row_off, const int* __restrict__ esrc,
        __half* __restrict__ out, int n) {
    const float LOG2E = 1.44269504f;
    int wave = threadIdx.x >> 6;
    int lane = threadIdx.x & 63;
    int node = blockIdx.x * 8 + wave;
    if (node >= n) return;
    int slot = lane >> 5;         // 0..1 : which edge of the phase
    unsigned jj = lane & 31;      // channels 8*jj .. 8*jj+7

    const uint4* xl16 = (const uint4*)xl;   // 32 uint4 per row

    f16x2 xrv[4];
    *(uint4*)(&xrv[0]) = ((const uint4*)xr)[((unsigned)node << 5) + jj];

    float4 a0 = *(const float4*)(att + jj * 8);
    float4 a1 = *(const float4*)(att + jj * 8 + 4);
    f16x2 atv[4] = {
        {(_Float16)(a0.x * LOG2E), (_Float16)(a0.y * LOG2E)},
        {(_Float16)(a0.z * LOG2E), (_Float16)(a0.w * LOG2E)},
        {(_Float16)(a1.x * LOG2E), (_Float16)(a1.y * LOG2E)},
        {(_Float16)(a1.z * LOG2E), (_Float16)(a1.w * LOG2E)}};
    const f16x2 k02 = {(_Float16)0.2f, (_Float16)0.2f};

    float acc[8] = {};
    float L = 0.f;

    int e0 = row_off[node], e1 = row_off[node + 1];
    int elast = (e1 > e0) ? e1 - 1 : 0;

    // prologue: srcs + 6 gathers covering edges e0 .. e0+11
    int sA = esrc[min(e0 +  0 + slot, elast)];
    int sB = esrc[min(e0 +  2 + slot, elast)];
    int sC = esrc[min(e0 +  4 + slot, elast)];
    int sD = esrc[min(e0 +  6 + slot, elast)];
    int sE = esrc[min(e0 +  8 + slot, elast)];
    int sF = esrc[min(e0 + 10 + slot, elast)];
    uint4 A = xl16[((unsigned)sA << 5) + jj];
    uint4 B = xl16[((unsigned)sB << 5) + jj];
    uint4 C = xl16[((unsigned)sC << 5) + jj];
    uint4 D = xl16[((unsigned)sD << 5) + jj];
    uint4 Ebuf = xl16[((unsigned)sE << 5) + jj];
    uint4 F = xl16[((unsigned)sF << 5) + jj];

#define H4_PHASE(BUF, EB)                                                     \
    {                                                                         \
        f16x2 v[4];                                                           \
        *(uint4*)(&v[0]) = BUF;                                               \
        float t = 0.f;                                                        \
        _Pragma("unroll")                                                     \
        for (int k = 0; k < 4; ++k) {                                         \
            f16x2 s = v[k] + xrv[k];                                          \
            f16x2 r = __builtin_elementwise_max(s, s * k02);                  \
            t = __builtin_amdgcn_fdot2(r, atv[k], t, false);                  \
        }                                                                     \
        t = dpp_add_f32<0xB1>(t);                                             \
        t = dpp_add_f32<0x4E>(t);                                             \
        t = dpp_add_f32<0x141>(t);                                            \
        float p = fast_exp2(t);                                               \
        p = ((EB) + slot < e1) ? p : 0.f;                                     \
        L += p;                                                               \
        _Pragma("unroll")                                                     \
        for (int k = 0; k < 4; ++k) {                                         \
            acc[2 * k]     = fmaf((float)v[k].x, p, acc[2 * k]);              \
            acc[2 * k + 1] = fmaf((float)v[k].y, p, acc[2 * k + 1]);          \
        }                                                                     \
    }

    {
        int e = e0;
        while (true) {
            int ns = esrc[min(e + 12 + slot, elast)];
            H4_PHASE(A, e)
            A = xl16[((unsigned)ns << 5) + jj];
            e += 2; if (e >= e1) break;
            ns = esrc[min(e + 12 + slot, elast)];
            H4_PHASE(B, e)
            B = xl16[((unsigned)ns << 5) + jj];
            e += 2; if (e >= e1) break;
            ns = esrc[min(e + 12 + slot, elast)];
            H4_PHASE(C, e)
            C = xl16[((unsigned)ns << 5) + jj];
            e += 2; if (e >= e1) break;
            ns = esrc[min(e + 12 + slot, elast)];
            H4_PHASE(D, e)
            D = xl16[((unsigned)ns << 5) + jj];
            e += 2; if (e >= e1) break;
            ns = esrc[min(e + 12 + slot, elast)];
            H4_PHASE(Ebuf, e)
            Ebuf = xl16[((unsigned)ns << 5) + jj];
            e += 2; if (e >= e1) break;
            ns = esrc[min(e + 12 + slot, elast)];
            H4_PHASE(F, e)
            F = xl16[((unsigned)ns << 5) + jj];
            e += 2; if (e >= e1) break;
        }
    }
#undef H4_PHASE

    // reduce partial sums across the 2 edge-slots (once per node)
#pragma unroll
    for (int k = 0; k < 8; ++k) acc[k] += __shfl_xor(acc[k], 32);
    L += __shfl_xor(L, 32);

    if (slot == 0) {
        float inv = 1.f / (L + 1e-16f);
        float4 b0 = *(const float4*)(bias + jj * 8);
        float4 b1v = *(const float4*)(bias + jj * 8 + 4);
        float bb[8] = {b0.x, b0.y, b0.z, b0.w, b1v.x, b1v.y, b1v.z, b1v.w};
        f16x8 o0;
#pragma unroll
        for (int k = 0; k < 8; ++k) {
            float vA = acc[k] * inv + bb[k];
            vA = vA > 0.f ? vA : __expf(vA) - 1.f;   // ELU
            o0[k] = (_Float16)vA;
        }
        *(f16x8*)((_Float16*)out + ((size_t)node << 8) + jj * 8) = o0;
    }
}

// ---------------------------------------------------------------------------
// GATv2 gather, H=1 x C=64 (no ELU). 8 lanes/edge x 8 slots, 3-buffer
// copy-free rotation, unconditional clamped refills, per-phase early exit,
// 512-thread blocks.
// ---------------------------------------------------------------------------
__global__ __launch_bounds__(512, 8) void gat_gather_h1(
        const __half* __restrict__ xl, const __half* __restrict__ xr,
        const float* __restrict__ att, const float* __restrict__ bias,
        const int* __restrict__ row_off, const int* __restrict__ esrc,
        __half* __restrict__ out, int n) {
    const float LOG2E = 1.44269504f;
    int wave = threadIdx.x >> 6;
    int lane = threadIdx.x & 63;
    int node = blockIdx.x * 8 + wave;
    if (node >= n) return;
    int eslot = lane >> 3;        // 0..7
    unsigned j = lane & 7;        // channels 8j .. 8j+7

    const uint4* xl16 = (const uint4*)xl;   // 8 uint4 per row

    f16x2 xrv[4];
    *(uint4*)(&xrv[0]) = ((const uint4*)xr)[((unsigned)node << 3) + j];

    float4 a0 = *(const float4*)(att + j * 8);
    float4 a1 = *(const float4*)(att + j * 8 + 4);
    f16x2 atv[4] = {
        {(_Float16)(a0.x * LOG2E), (_Float16)(a0.y * LOG2E)},
        {(_Float16)(a0.z * LOG2E), (_Float16)(a0.w * LOG2E)},
        {(_Float16)(a1.x * LOG2E), (_Float16)(a1.y * LOG2E)},
        {(_Float16)(a1.z * LOG2E), (_Float16)(a1.w * LOG2E)}};
    const f16x2 k02 = {(_Float16)0.2f, (_Float16)0.2f};

    float acc[8] = {};
    float L = 0.f;

    int e0 = row_off[node], e1 = row_off[node + 1];
    int elast = (e1 > e0) ? e1 - 1 : 0;

    // prologue: srcs + 3 gathers for edges e0 .. e0+23
    int sA = esrc[min(e0 +  0 + eslot, elast)];
    int sB = esrc[min(e0 +  8 + eslot, elast)];
    int sC = esrc[min(e0 + 16 + eslot, elast)];
    uint4 A = xl16[((unsigned)sA << 3) + j];
    uint4 B = xl16[((unsigned)sB << 3) + j];
    uint4 C = xl16[((unsigned)sC << 3) + j];

#define H1_PHASE(R, EB)                                                       \
    {                                                                         \
        f16x2 v[4];                                                           \
        *(uint4*)(&v[0]) = R;                                                 \
        float t0 = 0.f, t1 = 0.f;                                             \
        {                                                                     \
            f16x2 s0 = v[0] + xrv[0];                                         \
            f16x2 r0 = __builtin_elementwise_max(s0, s0 * k02);               \
            t0 = __builtin_amdgcn_fdot2(r0, atv[0], t0, false);               \
            f16x2 s1 = v[1] + xrv[1];                                         \
            f16x2 r1 = __builtin_elementwise_max(s1, s1 * k02);               \
            t0 = __builtin_amdgcn_fdot2(r1, atv[1], t0, false);               \
            f16x2 s2 = v[2] + xrv[2];                                         \
            f16x2 r2 = __builtin_elementwise_max(s2, s2 * k02);               \
            t1 = __builtin_amdgcn_fdot2(r2, atv[2], t1, false);               \
            f16x2 s3 = v[3] + xrv[3];                                         \
            f16x2 r3 = __builtin_elementwise_max(s3, s3 * k02);               \
            t1 = __builtin_amdgcn_fdot2(r3, atv[3], t1, false);               \
        }                                                                     \
        float t = t0 + t1;                                                    \
        t = dpp_add_f32<0xB1>(t);                                             \
        t = dpp_add_f32<0x4E>(t);                                             \
        t = dpp_add_f32<0x141>(t);                                            \
        float p = fast_exp2(t);                                               \
        p = ((EB) + eslot < e1) ? p : 0.f;                                    \
        L += p;                                                               \
        _Pragma("unroll")                                                     \
        for (int k = 0; k < 4; ++k) {                                         \
            acc[2 * k]     = fmaf((float)v[k].x, p, acc[2 * k]);              \
            acc[2 * k + 1] = fmaf((float)v[k].y, p, acc[2 * k + 1]);          \
        }                                                                     \
    }

    {
        int e = e0;
        while (true) {
            int ns = esrc[min(e + 24 + eslot, elast)];
            H1_PHASE(A, e)
            A = xl16[((unsigned)ns << 3) + j];
            e += 8; if (e >= e1) break;
            ns = esrc[min(e + 24 + eslot, elast)];
            H1_PHASE(B, e)
            B = xl16[((unsigned)ns << 3) + j];
            e += 8; if (e >= e1) break;
            ns = esrc[min(e + 24 + eslot, elast)];
            H1_PHASE(C, e)
            C = xl16[((unsigned)ns << 3) + j];
            e += 8; if (e >= e1) break;
        }
    }
#undef H1_PHASE

    // reduce partial sums across the 8 edge-slots
#pragma unroll
    for (int k = 0; k < 8; ++k) {
        acc[k] += __shfl_xor(acc[k], 8);
        acc[k] += __shfl_xor(acc[k], 16);
        acc[k] += __shfl_xor(acc[k], 32);
    }
    L += __shfl_xor(L, 8);
    L += __shfl_xor(L, 16);
    L += __shfl_xor(L, 32);

    if (eslot == 0) {
        float inv = 1.f / (L + 1e-16f);
        float4 b0 = *(const float4*)(bias + j * 8);
        float4 b1v = *(const float4*)(bias + j * 8 + 4);
        float bb[8] = {b0.x, b0.y, b0.z, b0.w, b1v.x, b1v.y, b1v.z, b1v.w};
        f16x8 ov;
#pragma unroll
        for (int k = 0; k < 8; ++k)
            ov[k] = (_Float16)(acc[k] * inv + bb[k]);
        *(f16x8*)((_Float16*)out + ((size_t)node << 6) + j * 8) = ov;
    }
}

// ---------------------------------------------------------------------------
extern "C" void kernel_launch(void* const* d_in, const int* in_sizes, int n_in,
                              void* d_out, int out_size, void* d_ws, size_t ws_size,
                              hipStream_t stream) {
    const float* x    = (const float*)d_in[0];
    const float* Wl1  = (const float*)d_in[1];
    const float* Wr1  = (const float*)d_in[2];
    const float* att1 = (const float*)d_in[3];
    const float* b1   = (const float*)d_in[4];
    const float* Wl2  = (const float*)d_in[5];
    const float* Wr2  = (const float*)d_in[6];
    const float* att2 = (const float*)d_in[7];
    const float* b2   = (const float*)d_in[8];
    const float* Wl3  = (const float*)d_in[9];
    const float* Wr3  = (const float*)d_in[10];
    const float* att3 = (const float*)d_in[11];
    const float* b3   = (const float*)d_in[12];
    const float* Wlin = (const float*)d_in[13];
    const float* blin = (const float*)d_in[14];
    const int*   ei   = (const int*)d_in[15];
    const int* src = ei;
    const int* dst = ei + EE;

    const int N = NN, E = EE;
    const int NB = (N + 255) / 256;             // 196 scan blocks

    __half* xf = (__half*)d_ws;                 // N*128
    __half* xl = xf + (size_t)N * 128;          // N*256
    __half* xr = xl + (size_t)N * 256;          // N*256
    __half* H  = xr + (size_t)N * 256;          // N*256
    __half* G  = H + (size_t)N * 256;           // N*64
    __half* w1 = G + (size_t)N * 64;            // 65536  frag-layout
    __half* w2 = w1 + 65536;                    // 131072
    __half* w3 = w2 + 131072;                   // 32768
    __half* w4 = w3 + 32768;                    // 4096
    int* row_off = (int*)(w4 + 4096);           // N+1
    int* tmp     = row_off + (N + 1);           // 2N (counts | cursor)
    int* esrc    = tmp + 2 * N;                 // E
    int* bsum    = esrc + E;                    // 256

    // --- build CSR by dst ---
    hipMemsetAsync(tmp, 0, (size_t)2 * N * sizeof(int), stream);
    hist_kernel<<<1024, 256, 0, stream>>>(dst, tmp, E);
    scan_phaseA<<<NB, 256, 0, stream>>>(tmp, bsum, N);
    scan_phaseB<<<1, 256, 0, stream>>>(bsum, row_off + N, NB);
    scan_phaseC<<<NB, 256, 0, stream>>>(tmp, bsum, row_off, N);
    scatter_kernel<<<1024, 256, 0, stream>>>(src, dst, row_off, tmp + N, esrc, E);

    // --- weights (fragment layout) + x -> fp16 ---
    int n4x = N * 128 / 4;
    prep_all<<<(233472 + n4x + 255) / 256, 256, 0, stream>>>(
        Wl1, Wr1, Wl2, Wr2, Wl3, Wr3, Wlin, w1, w2, w3, w4, x, xf, n4x);

    int nTiles = (N + 63) / 64;                 // 782
    int gatherBlocks = (N + 7) / 8;             // 512-thread blocks, 8 nodes

    // --- layer 1: xf[128] @ w1 -> xl,xr fp16 ---
    gemm_ws<4, 2><<<dim3(128, 4), 512, 0, stream>>>(
        xf, w1, N, nTiles, 512, 256, xl, xr, nullptr, nullptr);
    gat_gather_h4<<<gatherBlocks, 512, 0, stream>>>(xl, xr, att1, b1, row_off, esrc, H, N);

    // --- layer 2: H[256] @ w2 -> xl,xr ---
    gemm_ws<8, 2><<<dim3(128, 4), 512, 0, stream>>>(
        H, w2, N, nTiles, 512, 256, xl, xr, nullptr, nullptr);
    gat_gather_h4<<<gatherBlocks, 512, 0, stream>>>(xl, xr, att2, b2, row_off, esrc, H, N);

    // --- layer 3: H[256] @ w3 -> xl,xr ([N][64] each) ---
    gemm_ws<8, 2><<<dim3(256, 1), 512, 0, stream>>>(
        H, w3, N, nTiles, 128, 64, xl, xr, nullptr, nullptr);
    gat_gather_h1<<<gatherBlocks, 512, 0, stream>>>(xl, xr, att3, b3, row_off, esrc, G, N);

    // --- final: G[64] @ w4 + blin -> d_out fp32 ---
    gemm_ws<2, 1><<<dim3(512, 1), 256, 0, stream>>>(
        G, w4, N, nTiles, 64, 64, nullptr, nullptr, (float*)d_out, blin);
}